// Round 2
// baseline (1349.284 us; speedup 1.0000x reference)
//
#include <hip/hip_runtime.h>
#include <hip/hip_bf16.h>
#include <cstddef>

// Problem constants
#define D_MODEL 768
#define N_HEADS 12
#define D_HEAD 64
#define SEQ 2048
#define BATCH 2
#define NROWS (BATCH * SEQ)          // 4096
#define W_ELEMS (D_MODEL * D_MODEL)  // 589824
#define Y_ELEMS (NROWS * D_MODEL)    // 3145728
#define SCALE_C 0.125f               // 1/sqrt(64)

struct TTPtrs {
    const float* c0[4];
    const float* c1[4];
    const float* c2[4];
    const float* c3[4];
};

// ---------------------------------------------------------------------------
// Stage A: A[mi][pj][s] = sum_r c0[(m*4+i)*32+r] * c1[((r*4+p)*4+j)*64+s]
// sizes: mi in 16, pj in 16, s in 64  -> 16384 floats per matrix
// ---------------------------------------------------------------------------
__global__ __launch_bounds__(256) void tt_buildA(TTPtrs P, float* __restrict__ wsA) {
    const int mat = blockIdx.x;
    const float* c0 = P.c0[mat];
    const float* c1 = P.c1[mat];
    float* A = wsA + mat * 16384;
    for (int idx = threadIdx.x; idx < 16384; idx += 256) {
        int s  = idx & 63;
        int pj = (idx >> 6) & 15;
        int mi = idx >> 10;
        float acc = 0.f;
        #pragma unroll 8
        for (int r = 0; r < 32; r++) {
            acc = fmaf(c0[mi * 32 + r], c1[(r * 16 + pj) * 64 + s], acc);
        }
        A[idx] = acc;
    }
}

// ---------------------------------------------------------------------------
// Stage B: B[mi][pj][qk][t] = sum_s A[(mi*16+pj)*64+s] * c2[(s*36+qk)*32+t]
// sizes: 16*16*36*32 = 294912 floats per matrix
// ---------------------------------------------------------------------------
__global__ __launch_bounds__(256) void tt_buildB(TTPtrs P, const float* __restrict__ wsA,
                                                 float* __restrict__ wsB) {
    const int mat = blockIdx.y;
    const float* c2 = P.c2[mat];
    const float* A = wsA + mat * 16384;
    float* B = wsB + (size_t)mat * 294912;
    int idx = blockIdx.x * 256 + threadIdx.x;  // < 294912
    int t = idx & 31;
    int rest = idx >> 5;
    int qk = rest % 36;
    int rest2 = rest / 36;
    int pj = rest2 & 15;
    int mi = rest2 >> 4;
    const float* Arow = A + (mi * 16 + pj) * 64;
    float acc = 0.f;
    #pragma unroll 8
    for (int s = 0; s < 64; s++) {
        acc = fmaf(Arow[s], c2[(s * 36 + qk) * 32 + t], acc);
    }
    B[idx] = acc;
}

// ---------------------------------------------------------------------------
// Stage C: Wt[in][out] = sum_t B[((mi*16+pj)*36+qk)*32 + t] * c3[t*64 + u*8 + l]
//   out = ((m*4+p)*6+q)*8+u ; in = ((i*4+j)*6+k)*8+l ; mi=m*4+i etc.
// Wt stored transposed (in-major) so GEMM B-tile reads are coalesced.
// ---------------------------------------------------------------------------
__global__ __launch_bounds__(256) void tt_buildC(TTPtrs P, const float* __restrict__ wsB,
                                                 float* __restrict__ wsW) {
    const int mat = blockIdx.z;
    const float* c3 = P.c3[mat];
    const float* B = wsB + (size_t)mat * 294912;
    float* Wt = wsW + (size_t)mat * W_ELEMS;
    int out = blockIdx.x * 256 + threadIdx.x;  // < 768
    int in = blockIdx.y;                       // < 768
    int u = out & 7, q = (out >> 3) % 6, p = (out / 48) & 3, m = out / 192;
    int l = in & 7,  k = (in >> 3) % 6,  j = (in / 48) & 3,  i = in / 192;
    int mi = m * 4 + i, pj = p * 4 + j, qk = q * 6 + k;
    const float* Brow = B + ((size_t)(mi * 16 + pj) * 36 + qk) * 32;
    const float* c3row = c3 + u * 8 + l;
    float acc = 0.f;
    #pragma unroll 8
    for (int t = 0; t < 32; t++) {
        acc = fmaf(Brow[t], c3row[t * 64], acc);
    }
    Wt[(size_t)in * D_MODEL + out] = acc;
}

// ---------------------------------------------------------------------------
// GEMM: Y[n][out] = sum_in X[n][in] * Wt[in][out] + bias[out]
// M=4096 (rows), N=768 (out), K=768 (in). BM=BN=128, BK=8, 256 thr, 8x8/thr.
// blockIdx.z selects matrix (for fused q/k/v launch).
// ---------------------------------------------------------------------------
__global__ __launch_bounds__(256) void gemm_bias(const float* __restrict__ X,
                                                 const float* __restrict__ Wbase,
                                                 const float* __restrict__ b0,
                                                 const float* __restrict__ b1,
                                                 const float* __restrict__ b2,
                                                 float* __restrict__ Ybase) {
    const int z = blockIdx.z;
    const float* W = Wbase + (size_t)z * W_ELEMS;
    const float* bias = (z == 0) ? b0 : ((z == 1) ? b1 : b2);
    float* Y = Ybase + (size_t)z * Y_ELEMS;

    __shared__ float As[8][128];   // [k][m]
    __shared__ float Bs[8][128];   // [k][n]

    const int tid = threadIdx.x;
    const int m0 = blockIdx.x * 128, n0 = blockIdx.y * 128;
    const int lr = tid >> 1, lc = (tid & 1) << 2;   // A-tile load coords
    const int br = tid >> 5, bc = (tid & 31) << 2;  // B-tile load coords
    const int ty = tid >> 4, tx = tid & 15;

    float acc[8][8];
    #pragma unroll
    for (int i = 0; i < 8; i++)
        #pragma unroll
        for (int jj = 0; jj < 8; jj++) acc[i][jj] = 0.f;

    for (int k0 = 0; k0 < D_MODEL; k0 += 8) {
        float4 av = *(const float4*)&X[(size_t)(m0 + lr) * D_MODEL + k0 + lc];
        float4 bv = *(const float4*)&W[(size_t)(k0 + br) * D_MODEL + n0 + bc];
        __syncthreads();
        As[lc + 0][lr] = av.x;
        As[lc + 1][lr] = av.y;
        As[lc + 2][lr] = av.z;
        As[lc + 3][lr] = av.w;
        *(float4*)&Bs[br][bc] = bv;
        __syncthreads();
        #pragma unroll
        for (int kk = 0; kk < 8; kk++) {
            float4 a0 = *(const float4*)&As[kk][ty * 8];
            float4 a1 = *(const float4*)&As[kk][ty * 8 + 4];
            float4 e0 = *(const float4*)&Bs[kk][tx * 8];
            float4 e1 = *(const float4*)&Bs[kk][tx * 8 + 4];
            float a[8] = {a0.x, a0.y, a0.z, a0.w, a1.x, a1.y, a1.z, a1.w};
            float bb[8] = {e0.x, e0.y, e0.z, e0.w, e1.x, e1.y, e1.z, e1.w};
            #pragma unroll
            for (int i = 0; i < 8; i++)
                #pragma unroll
                for (int jj = 0; jj < 8; jj++)
                    acc[i][jj] = fmaf(a[i], bb[jj], acc[i][jj]);
        }
    }

    float bb[8];
    #pragma unroll
    for (int jj = 0; jj < 8; jj++) bb[jj] = bias[n0 + tx * 8 + jj];
    #pragma unroll
    for (int i = 0; i < 8; i++) {
        float4 o0 = make_float4(acc[i][0] + bb[0], acc[i][1] + bb[1],
                                acc[i][2] + bb[2], acc[i][3] + bb[3]);
        float4 o1 = make_float4(acc[i][4] + bb[4], acc[i][5] + bb[5],
                                acc[i][6] + bb[6], acc[i][7] + bb[7]);
        float4* dst = (float4*)&Y[(size_t)(m0 + ty * 8 + i) * D_MODEL + n0 + tx * 8];
        dst[0] = o0;
        dst[1] = o1;
    }
}

// ---------------------------------------------------------------------------
// Causal flash attention, fp32. 16 q-rows/block (4 per wave), K/V tiles of 64.
// Lane owns output dim d=lane. Online softmax, P staged via LDS broadcasts.
// ---------------------------------------------------------------------------
__global__ __launch_bounds__(256) void attn_kernel(const float* __restrict__ Q,
                                                   const float* __restrict__ K,
                                                   const float* __restrict__ V,
                                                   float* __restrict__ O) {
    __shared__ float ks[64][68];  // padded: rows 272B, 16B-aligned, conflict-light
    __shared__ float vs[64][68];
    __shared__ float qs[16][64];
    __shared__ float ps[16][64];

    const int bx = blockIdx.x;
    const int qt = bx & 127;   // q-tile (16 rows each)
    const int bh = bx >> 7;    // 0..23
    const int b = bh / N_HEADS, h = bh % N_HEADS;
    const int tid = threadIdx.x, w = tid >> 6, lane = tid & 63;

    // load 16 q rows
    for (int e = tid; e < 1024; e += 256) {
        int r = e >> 6, c = e & 63;
        qs[r][c] = Q[((size_t)(b * SEQ + qt * 16 + r)) * D_MODEL + h * 64 + c];
    }

    const int q0 = qt * 16 + w * 4;  // wave's first q row
    float m_[4] = {-1e30f, -1e30f, -1e30f, -1e30f};
    float l_[4] = {0.f, 0.f, 0.f, 0.f};
    float acc[4] = {0.f, 0.f, 0.f, 0.f};

    const int ntile = (qt >> 2) + 1;  // tiles of 64 keys covering causal range
    for (int kt = 0; kt < ntile; kt++) {
        __syncthreads();
        for (int e = tid; e < 4096; e += 256) {
            int r = e >> 6, c = e & 63;
            size_t g = ((size_t)(b * SEQ + kt * 64 + r)) * D_MODEL + h * 64 + c;
            ks[r][c] = K[g];
            vs[r][c] = V[g];
        }
        __syncthreads();

        // scores: lane computes key = kt*64+lane vs 4 q rows
        const int key = kt * 64 + lane;
        float s_[4] = {0.f, 0.f, 0.f, 0.f};
        #pragma unroll
        for (int d4 = 0; d4 < 16; d4++) {
            float4 kv = *(const float4*)&ks[lane][d4 * 4];
            #pragma unroll
            for (int r = 0; r < 4; r++) {
                float4 qv = *(const float4*)&qs[w * 4 + r][d4 * 4];
                s_[r] += kv.x * qv.x + kv.y * qv.y + kv.z * qv.z + kv.w * qv.w;
            }
        }
        #pragma unroll
        for (int r = 0; r < 4; r++) {
            float s = s_[r] * SCALE_C;
            if (key > q0 + r) s = -10000.0f;
            float smax = s;
            #pragma unroll
            for (int off = 32; off; off >>= 1) smax = fmaxf(smax, __shfl_xor(smax, off));
            float mnew = fmaxf(m_[r], smax);
            float p = __expf(s - mnew);
            float alpha = __expf(m_[r] - mnew);
            float psum = p;
            #pragma unroll
            for (int off = 32; off; off >>= 1) psum += __shfl_xor(psum, off);
            l_[r] = l_[r] * alpha + psum;
            acc[r] *= alpha;
            m_[r] = mnew;
            ps[w * 4 + r][lane] = p;
        }
        // PV: acc[r] += sum_e ps[r][e] * vs[e][lane]
        #pragma unroll 4
        for (int e4 = 0; e4 < 16; e4++) {
            float4 p0 = *(const float4*)&ps[w * 4 + 0][e4 * 4];
            float4 p1 = *(const float4*)&ps[w * 4 + 1][e4 * 4];
            float4 p2 = *(const float4*)&ps[w * 4 + 2][e4 * 4];
            float4 p3 = *(const float4*)&ps[w * 4 + 3][e4 * 4];
            float v0 = vs[e4 * 4 + 0][lane];
            float v1 = vs[e4 * 4 + 1][lane];
            float v2 = vs[e4 * 4 + 2][lane];
            float v3 = vs[e4 * 4 + 3][lane];
            acc[0] += p0.x * v0 + p0.y * v1 + p0.z * v2 + p0.w * v3;
            acc[1] += p1.x * v0 + p1.y * v1 + p1.z * v2 + p1.w * v3;
            acc[2] += p2.x * v0 + p2.y * v1 + p2.z * v2 + p2.w * v3;
            acc[3] += p3.x * v0 + p3.y * v1 + p3.z * v2 + p3.w * v3;
        }
    }

    #pragma unroll
    for (int r = 0; r < 4; r++) {
        O[((size_t)(b * SEQ + q0 + r)) * D_MODEL + h * 64 + lane] = acc[r] / l_[r];
    }
}

// ---------------------------------------------------------------------------
// Workspace layout (floats):
//   wsA  @ 0        (65536)      \ dead after build; overlapped by wsO
//   wsB  @ 65536    (1179648)    /
//   wsO  @ 0        (3145728)   attention output (reuses A/B region)
//   wsW  @ 3145728  (4*589824 = 2359296)
//   wsQ  @ 5505024  (3145728)
//   wsK  @ 8650752  (3145728)
//   wsV  @ 11796480 (3145728)
//   total 14942208 floats = 59.8 MB
// ---------------------------------------------------------------------------
extern "C" void kernel_launch(void* const* d_in, const int* in_sizes, int n_in,
                              void* d_out, int out_size, void* d_ws, size_t ws_size,
                              hipStream_t stream) {
    const float* x = (const float*)d_in[0];
    // d_in[1] is the causal mask — deterministic, ignored.
    TTPtrs P;
    const float* biases[4];
    const int base[4] = {2, 7, 12, 17};  // q, k, v, o parameter groups
    for (int t = 0; t < 4; t++) {
        P.c0[t] = (const float*)d_in[base[t] + 0];
        P.c1[t] = (const float*)d_in[base[t] + 1];
        P.c2[t] = (const float*)d_in[base[t] + 2];
        P.c3[t] = (const float*)d_in[base[t] + 3];
        biases[t] = (const float*)d_in[base[t] + 4];
    }

    float* ws = (float*)d_ws;
    float* wsA = ws;
    float* wsB = ws + 65536;
    float* wsO = ws;  // overlaps A/B (dead by attention time)
    float* wsW = ws + 3145728;
    float* wsQ = wsW + 4 * (size_t)W_ELEMS;  // note: wsW holds 4 matrices
    float* wsK = wsQ + Y_ELEMS;
    float* wsV = wsK + Y_ELEMS;

    // Build the four 768x768 weight matrices (stored transposed: [in][out])
    tt_buildA<<<dim3(4), 256, 0, stream>>>(P, wsA);
    tt_buildB<<<dim3(1152, 4), 256, 0, stream>>>(P, wsA, wsB);
    tt_buildC<<<dim3(3, 768, 4), 256, 0, stream>>>(P, wsB, wsW);

    // q, k, v projections (one launch, grid.z selects matrix)
    gemm_bias<<<dim3(32, 6, 3), 256, 0, stream>>>(x, wsW, biases[0], biases[1],
                                                  biases[2], wsQ);

    // causal attention
    attn_kernel<<<dim3(2 * N_HEADS * (SEQ / 16)), 256, 0, stream>>>(wsQ, wsK, wsV, wsO);

    // output projection -> d_out
    gemm_bias<<<dim3(32, 6, 1), 256, 0, stream>>>(wsO, wsW + 3 * (size_t)W_ELEMS,
                                                  biases[3], biases[3], biases[3],
                                                  (float*)d_out);
}

// Round 3
// 308.520 us; speedup vs baseline: 4.3734x; 4.3734x over previous
//
#include <hip/hip_runtime.h>
#include <cstddef>
#include <cstdint>

// Problem constants
#define D_MODEL 768
#define N_HEADS 12
#define SEQ 2048
#define BATCH 2
#define NROWS (BATCH * SEQ)          // 4096
#define W_ELEMS (D_MODEL * D_MODEL)  // 589824
#define Y_ELEMS (NROWS * D_MODEL)    // 3145728

typedef __attribute__((ext_vector_type(8))) short bf16x8;
typedef __attribute__((ext_vector_type(4))) float f32x4;

struct TTPtrs {
    const float* c0[4];
    const float* c1[4];
    const float* c2[4];
    const float* c3[4];
};

__device__ __forceinline__ float bf2f(uint16_t u) {
    union { uint32_t u; float f; } c; c.u = ((uint32_t)u) << 16; return c.f;
}
__device__ __forceinline__ uint16_t f2bf(float f) {
    union { float f; uint32_t u; } c; c.f = f;
    uint32_t x = c.u + 0x7fffu + ((c.u >> 16) & 1u);   // RNE
    return (uint16_t)(x >> 16);
}
// global->LDS direct copy, 16B per lane; LDS dest = wave-uniform base + lane*16
__device__ __forceinline__ void glds16(const void* g, void* l) {
    auto gp = reinterpret_cast<const __attribute__((address_space(1))) uint32_t*>(
        reinterpret_cast<uintptr_t>(g));
    auto lp = reinterpret_cast<__attribute__((address_space(3))) uint32_t*>(
        reinterpret_cast<uintptr_t>(l));
    __builtin_amdgcn_global_load_lds(gp, lp, 16, 0, 0);
}

// ---------------------------------------------------------------------------
// TT weight build (fp32, tiny). Stage A: A[mi][pj][s], 16x16x64 per matrix.
// ---------------------------------------------------------------------------
__global__ __launch_bounds__(256) void tt_buildA(TTPtrs P, float* __restrict__ wsA) {
    const int mat = blockIdx.x;
    const float* c0 = P.c0[mat];
    const float* c1 = P.c1[mat];
    float* A = wsA + mat * 16384;
    for (int idx = threadIdx.x; idx < 16384; idx += 256) {
        int s = idx & 63, pj = (idx >> 6) & 15, mi = idx >> 10;
        float acc = 0.f;
        #pragma unroll 8
        for (int r = 0; r < 32; r++)
            acc = fmaf(c0[mi * 32 + r], c1[(r * 16 + pj) * 64 + s], acc);
        A[idx] = acc;
    }
}

// Stage B: B[mi][pj][qk][t] = sum_s A * c2, 16*16*36*32 per matrix
__global__ __launch_bounds__(256) void tt_buildB(TTPtrs P, const float* __restrict__ wsA,
                                                 float* __restrict__ wsB) {
    const int mat = blockIdx.y;
    const float* c2 = P.c2[mat];
    const float* A = wsA + mat * 16384;
    float* B = wsB + (size_t)mat * 294912;
    int idx = blockIdx.x * 256 + threadIdx.x;
    int t = idx & 31;
    int rest = idx >> 5;
    int qk = rest % 36;
    int rest2 = rest / 36;
    int pj = rest2 & 15, mi = rest2 >> 4;
    const float* Arow = A + (mi * 16 + pj) * 64;
    float acc = 0.f;
    #pragma unroll 8
    for (int s = 0; s < 64; s++)
        acc = fmaf(Arow[s], c2[(s * 36 + qk) * 32 + t], acc);
    B[idx] = acc;
}

// Stage C: Wbf[mat][out][in] (bf16) = sum_t B * c3.  out = blockIdx.y, in = thread
// (in-major thread mapping -> coalesced 2B stores along `in`)
__global__ __launch_bounds__(256) void tt_buildC(TTPtrs P, const float* __restrict__ wsB,
                                                 uint16_t* __restrict__ Wbf) {
    const int mat = blockIdx.z;
    const float* c3 = P.c3[mat];
    const float* B = wsB + (size_t)mat * 294912;
    uint16_t* Wt = Wbf + (size_t)mat * W_ELEMS;
    int in = blockIdx.x * 256 + threadIdx.x;   // < 768
    int out = blockIdx.y;                      // < 768
    int u = out & 7, q = (out >> 3) % 6, p = (out / 48) & 3, m = out / 192;
    int l = in & 7,  k = (in >> 3) % 6,  j = (in / 48) & 3,  i = in / 192;
    int mi = m * 4 + i, pj = p * 4 + j, qk = q * 6 + k;
    const float* Brow = B + ((size_t)(mi * 16 + pj) * 36 + qk) * 32;
    const float* c3row = c3 + u * 8 + l;
    float acc = 0.f;
    #pragma unroll 8
    for (int t = 0; t < 32; t++)
        acc = fmaf(Brow[t], c3row[t * 64], acc);
    Wt[(size_t)out * D_MODEL + in] = f2bf(acc);
}

// x (fp32) -> bf16
__global__ __launch_bounds__(256) void x2bf_kernel(const float* __restrict__ x,
                                                   uint16_t* __restrict__ xb) {
    int idx = (blockIdx.x * 256 + threadIdx.x) * 4;
    float4 v = *(const float4*)(x + idx);
    uint32_t lo = (uint32_t)f2bf(v.x) | ((uint32_t)f2bf(v.y) << 16);
    uint32_t hi = (uint32_t)f2bf(v.z) | ((uint32_t)f2bf(v.w) << 16);
    *(uint2*)(xb + idx) = make_uint2(lo, hi);
}

// ---------------------------------------------------------------------------
// bf16 MFMA GEMM: Y[row][out] = sum_in X[row][in] * W[out][in] + bias[out]
// 128x128 tile, BK=32, 4 waves (2x2 of 64x64), global_load_lds staging with
// pre-swizzled source (XOR c16 ^= row&3) to cut ds_read_b128 bank conflicts.
// One barrier per K-step (T3 minimum 2-phase), LDS double-buffered.
// ---------------------------------------------------------------------------
template <int OUT_BF16>
__global__ __launch_bounds__(256) void gemm_mfma(const uint16_t* __restrict__ X,
                                                 const uint16_t* __restrict__ Wall,
                                                 const float* __restrict__ b0,
                                                 const float* __restrict__ b1,
                                                 const float* __restrict__ b2,
                                                 void* __restrict__ Yall) {
    __shared__ uint16_t lds[2][8192];  // per buf: A tile [0,4096), B tile [4096,8192)
    const int z = blockIdx.z;
    const uint16_t* W = Wall + (size_t)z * W_ELEMS;
    const float* bias = (z == 0) ? b0 : (z == 1 ? b1 : b2);
    const int m0 = blockIdx.x * 128, n0 = blockIdx.y * 128;
    const int tid = threadIdx.x, w = tid >> 6, l = tid & 63;
    const int wr = w >> 1, wc = w & 1;
    const int l15 = l & 15, lg = l >> 4;

    // staging: wave w covers tile rows w*32 .. w*32+31 (2 glds of 16 rows each)
    const int srow = w * 32 + (l >> 2);
    const int scol = ((l & 3) ^ ((l >> 2) & 3)) * 8;  // inverse-swizzled source c16
    const uint16_t* Abase = X + (size_t)(m0 + srow) * D_MODEL + scol;
    const uint16_t* Bbase = W + (size_t)(n0 + srow) * D_MODEL + scol;

    f32x4 acc[4][4];
    #pragma unroll
    for (int mi = 0; mi < 4; ++mi)
        #pragma unroll
        for (int ni = 0; ni < 4; ++ni) acc[mi][ni] = (f32x4){0.f, 0.f, 0.f, 0.f};

    auto stage = [&](int buf, int kt) {
        const uint16_t* A0 = Abase + kt * 32;
        const uint16_t* B0 = Bbase + kt * 32;
        glds16(A0, &lds[buf][w * 1024]);
        glds16(A0 + 16 * D_MODEL, &lds[buf][w * 1024 + 512]);
        glds16(B0, &lds[buf][4096 + w * 1024]);
        glds16(B0 + 16 * D_MODEL, &lds[buf][4096 + w * 1024 + 512]);
    };

    stage(0, 0);
    __syncthreads();
    const int roff = ((lg ^ (l & 3)) << 3);  // swizzled ushort offset within 32-wide row
    for (int kt = 0; kt < 24; ++kt) {
        int cur = kt & 1;
        if (kt < 23) stage(cur ^ 1, kt + 1);
        const uint16_t* As = &lds[cur][0];
        const uint16_t* Bs = &lds[cur][4096];
        bf16x8 a[4], bb[4];
        #pragma unroll
        for (int mi = 0; mi < 4; ++mi)
            a[mi] = *(const bf16x8*)(As + (wr * 64 + mi * 16 + l15) * 32 + roff);
        #pragma unroll
        for (int ni = 0; ni < 4; ++ni)
            bb[ni] = *(const bf16x8*)(Bs + (wc * 64 + ni * 16 + l15) * 32 + roff);
        #pragma unroll
        for (int mi = 0; mi < 4; ++mi)
            #pragma unroll
            for (int ni = 0; ni < 4; ++ni)
                acc[mi][ni] = __builtin_amdgcn_mfma_f32_16x16x32_bf16(
                    a[mi], bb[ni], acc[mi][ni], 0, 0, 0);
        __syncthreads();
    }

    float bv[4];
    #pragma unroll
    for (int ni = 0; ni < 4; ++ni) bv[ni] = bias[n0 + wc * 64 + ni * 16 + l15];
    #pragma unroll
    for (int mi = 0; mi < 4; ++mi)
        #pragma unroll
        for (int ni = 0; ni < 4; ++ni)
            #pragma unroll
            for (int r = 0; r < 4; ++r) {
                int row = m0 + wr * 64 + mi * 16 + lg * 4 + r;
                int col = n0 + wc * 64 + ni * 16 + l15;
                float v = acc[mi][ni][r] + bv[ni];
                if (OUT_BF16)
                    ((uint16_t*)Yall + (size_t)z * Y_ELEMS)[(size_t)row * D_MODEL + col] = f2bf(v);
                else
                    ((float*)Yall)[(size_t)row * D_MODEL + col] = v;
            }
}

// ---------------------------------------------------------------------------
// Causal flash attention, bf16 MFMA. Block = one (b,h) x 64 q-rows, 4 waves
// of 16 q-rows. Swapped S^T = K*Qs^T so softmax reduce is mostly lane-local.
// K staged via glds (pre-swizzled source), V transpose-scattered to LDS,
// P routed through per-wave LDS; all tiles XOR-swizzled (^((row&7)<<4)).
// ---------------------------------------------------------------------------
__global__ __launch_bounds__(256) void attn_mfma(const uint16_t* __restrict__ Q,
                                                 const uint16_t* __restrict__ K,
                                                 const uint16_t* __restrict__ V,
                                                 uint16_t* __restrict__ O) {
    __shared__ uint16_t ks[4096];      // K tile [64 key][64 d], swizzled
    __shared__ uint16_t vt[4096];      // V^T tile [64 d][64 key], swizzled
    __shared__ uint16_t ps[4][1024];   // per-wave P [16 q][64 key], swizzled

    const int bx = blockIdx.x;
    const int qt = 31 - bx / 24;       // big causal tiles scheduled first
    const int bh = bx % 24;
    const int b = bh / 12, h = bh % 12;
    const int tid = threadIdx.x, w = tid >> 6, l = tid & 63;
    const int l15 = l & 15, lg = l >> 4;
    const size_t headoff = (size_t)b * SEQ * D_MODEL + h * 64;

    // Q B-frags (col = q, k = d), pre-scaled by 1/8 (exact in bf16)
    bf16x8 qf[2];
    {
        const uint16_t* qp = Q + headoff + (size_t)(qt * 64 + w * 16 + l15) * D_MODEL + lg * 8;
        #pragma unroll
        for (int ds = 0; ds < 2; ++ds) {
            bf16x8 qv = *(const bf16x8*)(qp + ds * 32);
            #pragma unroll
            for (int j = 0; j < 8; ++j)
                qf[ds][j] = (short)f2bf(bf2f((uint16_t)qv[j]) * 0.125f);
        }
    }

    float m_ = -3e38f, l_ = 0.f;
    f32x4 oacc[4];
    #pragma unroll
    for (int ni = 0; ni < 4; ++ni) oacc[ni] = (f32x4){0.f, 0.f, 0.f, 0.f};
    const int qglob = qt * 64 + w * 16 + l15;

    for (int kt = 0; kt <= qt; ++kt) {
        __syncthreads();  // previous tile fully consumed before restaging
        {   // K: wave w stages key rows w*16..w*16+15, source pre-swizzled
            const uint16_t* ksrc = K + headoff +
                (size_t)(kt * 64 + w * 16 + (l >> 3)) * D_MODEL +
                (((l & 7) ^ ((l >> 3) & 7)) * 8);
            glds16(ksrc, &ks[w * 1024]);
            glds16(ksrc + 8 * D_MODEL, &ks[w * 1024 + 512]);
        }
        {   // V^T: lane owns key=l, d-range w*16..w*16+15; 2B scatter (conflict-free)
            const uint16_t* vsrc = V + headoff + (size_t)(kt * 64 + l) * D_MODEL + w * 16;
            #pragma unroll
            for (int c = 0; c < 2; ++c) {
                bf16x8 vv = *(const bf16x8*)(vsrc + c * 8);
                #pragma unroll
                for (int j = 0; j < 8; ++j) {
                    int d = w * 16 + c * 8 + j;
                    int byte = (d * 128 + l * 2) ^ ((d & 7) << 4);
                    vt[byte >> 1] = (uint16_t)vv[j];
                }
            }
        }
        __syncthreads();

        // S^T[key][q] = K · Qs^T
        f32x4 sacc[4];
        #pragma unroll
        for (int ki = 0; ki < 4; ++ki) sacc[ki] = (f32x4){0.f, 0.f, 0.f, 0.f};
        #pragma unroll
        for (int ds = 0; ds < 2; ++ds)
            #pragma unroll
            for (int ki = 0; ki < 4; ++ki) {
                int byte = (ki * 16 + l15) * 128 + ((((ds << 2) + lg) ^ (l & 7)) << 4);
                bf16x8 ak = *(const bf16x8*)((const char*)ks + byte);
                sacc[ki] = __builtin_amdgcn_mfma_f32_16x16x32_bf16(ak, qf[ds], sacc[ki], 0, 0, 0);
            }

        // online softmax; lane's q = l15, lane holds 16 keys (4 frags x 4 regs)
        float pvv[16];
        float mx = -3e38f;
        #pragma unroll
        for (int ki = 0; ki < 4; ++ki)
            #pragma unroll
            for (int r = 0; r < 4; ++r) {
                int key = kt * 64 + ki * 16 + lg * 4 + r;
                float s = (key <= qglob) ? sacc[ki][r] : -3e38f;
                pvv[ki * 4 + r] = s;
                mx = fmaxf(mx, s);
            }
        mx = fmaxf(mx, __shfl_xor(mx, 16));
        mx = fmaxf(mx, __shfl_xor(mx, 32));
        float mnew = fmaxf(m_, mx);
        float sum = 0.f;
        uint32_t pk[8];
        #pragma unroll
        for (int i = 0; i < 16; i += 2) {
            float p0 = __expf(pvv[i] - mnew);
            float p1 = __expf(pvv[i + 1] - mnew);
            sum += p0 + p1;
            pk[i >> 1] = (uint32_t)f2bf(p0) | ((uint32_t)f2bf(p1) << 16);
        }
        sum += __shfl_xor(sum, 16);
        sum += __shfl_xor(sum, 32);
        float alpha = __expf(m_ - mnew);
        l_ = l_ * alpha + sum;
        m_ = mnew;

        // rescale O acc (its q-row = lg*4 + r; fetch that q's alpha from lane q)
        float a0 = __shfl(alpha, lg * 4 + 0), a1 = __shfl(alpha, lg * 4 + 1);
        float a2 = __shfl(alpha, lg * 4 + 2), a3 = __shfl(alpha, lg * 4 + 3);
        #pragma unroll
        for (int ni = 0; ni < 4; ++ni) {
            oacc[ni][0] *= a0; oacc[ni][1] *= a1;
            oacc[ni][2] *= a2; oacc[ni][3] *= a3;
        }

        // write P (4 consecutive keys per b64, swizzled); wave-private region
        uint16_t* psw = &ps[w][0];
        #pragma unroll
        for (int ki = 0; ki < 4; ++ki) {
            int byte = (l15 * 128 + ki * 32 + lg * 8) ^ ((l15 & 7) << 4);
            *(uint2*)((char*)psw + byte) = make_uint2(pk[ki * 2], pk[ki * 2 + 1]);
        }
        asm volatile("s_waitcnt lgkmcnt(0)" ::: "memory");

        // O[q][d] += P · V
        #pragma unroll
        for (int kss = 0; kss < 2; ++kss) {
            int pbyte = l15 * 128 + ((((kss << 2) + lg) ^ (l15 & 7)) << 4);
            bf16x8 ap = *(const bf16x8*)((const char*)psw + pbyte);
            #pragma unroll
            for (int ni = 0; ni < 4; ++ni) {
                int vbyte = (ni * 16 + l15) * 128 + ((((kss << 2) + lg) ^ (l15 & 7)) << 4);
                bf16x8 bv = *(const bf16x8*)((const char*)vt + vbyte);
                oacc[ni] = __builtin_amdgcn_mfma_f32_16x16x32_bf16(ap, bv, oacc[ni], 0, 0, 0);
            }
        }
    }

    float li0 = 1.f / __shfl(l_, lg * 4 + 0), li1 = 1.f / __shfl(l_, lg * 4 + 1);
    float li2 = 1.f / __shfl(l_, lg * 4 + 2), li3 = 1.f / __shfl(l_, lg * 4 + 3);
    #pragma unroll
    for (int ni = 0; ni < 4; ++ni) {
        int col = h * 64 + ni * 16 + l15;
        size_t rb = (size_t)(b * SEQ + qt * 64 + w * 16 + lg * 4) * D_MODEL + col;
        O[rb + 0 * D_MODEL] = f2bf(oacc[ni][0] * li0);
        O[rb + 1 * D_MODEL] = f2bf(oacc[ni][1] * li1);
        O[rb + 2 * D_MODEL] = f2bf(oacc[ni][2] * li2);
        O[rb + 3 * D_MODEL] = f2bf(oacc[ni][3] * li3);
    }
}

// ---------------------------------------------------------------------------
// Workspace (bytes):
//   wsA  @ 0         262144   fp32
//   wsB  @ 262144    4718592  fp32
//   Wbf  @ 4980736   4718592  bf16 [4][out][in]
//   xbf  @ 9699328   6291456
//   Qbf  @ 15990784  6291456  \
//   Kbf  @ 22282240  6291456   } contiguous so QKV gemm indexes z*Y_ELEMS
//   Vbf  @ 28573696  6291456  /
//   Obf  @ 34865152  6291456   total ~41.2 MB
// ---------------------------------------------------------------------------
extern "C" void kernel_launch(void* const* d_in, const int* in_sizes, int n_in,
                              void* d_out, int out_size, void* d_ws, size_t ws_size,
                              hipStream_t stream) {
    const float* x = (const float*)d_in[0];
    TTPtrs P;
    const float* biases[4];
    const int base[4] = {2, 7, 12, 17};  // q, k, v, o parameter groups
    for (int t = 0; t < 4; t++) {
        P.c0[t] = (const float*)d_in[base[t] + 0];
        P.c1[t] = (const float*)d_in[base[t] + 1];
        P.c2[t] = (const float*)d_in[base[t] + 2];
        P.c3[t] = (const float*)d_in[base[t] + 3];
        biases[t] = (const float*)d_in[base[t] + 4];
    }

    char* ws = (char*)d_ws;
    float* wsA = (float*)(ws + 0);
    float* wsB = (float*)(ws + 262144);
    uint16_t* Wbf = (uint16_t*)(ws + 4980736);
    uint16_t* xbf = (uint16_t*)(ws + 9699328);
    uint16_t* Qbf = (uint16_t*)(ws + 15990784);
    uint16_t* Kbf = (uint16_t*)(ws + 22282240);
    uint16_t* Vbf = (uint16_t*)(ws + 28573696);
    uint16_t* Obf = (uint16_t*)(ws + 34865152);

    tt_buildA<<<dim3(4), 256, 0, stream>>>(P, wsA);
    tt_buildB<<<dim3(1152, 4), 256, 0, stream>>>(P, wsA, wsB);
    tt_buildC<<<dim3(3, 768, 4), 256, 0, stream>>>(P, wsB, Wbf);
    x2bf_kernel<<<dim3(3072), 256, 0, stream>>>(x, xbf);

    // q, k, v projections (bf16 out)
    gemm_mfma<1><<<dim3(32, 6, 3), 256, 0, stream>>>(xbf, Wbf, biases[0], biases[1],
                                                     biases[2], (void*)Qbf);
    // causal attention (bf16 out)
    attn_mfma<<<dim3(24 * 32), 256, 0, stream>>>(Qbf, Kbf, Vbf, Obf);

    // output projection (fp32 out -> d_out)
    gemm_mfma<0><<<dim3(32, 6, 1), 256, 0, stream>>>(Obf, Wbf + 3 * (size_t)W_ELEMS,
                                                     biases[3], biases[3], biases[3],
                                                     d_out);
}

// Round 4
// 243.432 us; speedup vs baseline: 5.5428x; 1.2674x over previous
//
#include <hip/hip_runtime.h>
#include <cstddef>
#include <cstdint>

// Problem constants
#define D_MODEL 768
#define N_HEADS 12
#define SEQ 2048
#define BATCH 2
#define NROWS (BATCH * SEQ)          // 4096
#define W_ELEMS (D_MODEL * D_MODEL)  // 589824
#define Y_ELEMS (NROWS * D_MODEL)    // 3145728

typedef __attribute__((ext_vector_type(8))) short bf16x8;
typedef __attribute__((ext_vector_type(4))) float f32x4;

struct TTPtrs {
    const float* c0[4];
    const float* c1[4];
    const float* c2[4];
    const float* c3[4];
};

__device__ __forceinline__ float bf2f(uint16_t u) {
    union { uint32_t u; float f; } c; c.u = ((uint32_t)u) << 16; return c.f;
}
__device__ __forceinline__ uint16_t f2bf(float f) {
    union { float f; uint32_t u; } c; c.f = f;
    uint32_t x = c.u + 0x7fffu + ((c.u >> 16) & 1u);   // RNE
    return (uint16_t)(x >> 16);
}
// pack two f32 -> 2x bf16 in one VALU op (T12 recipe; no builtin on gfx950)
__device__ __forceinline__ uint32_t cvtpk(float lo, float hi) {
    uint32_t r;
    asm("v_cvt_pk_bf16_f32 %0, %1, %2" : "=v"(r) : "v"(lo), "v"(hi));
    return r;
}
// global->LDS direct copy, 16B per lane; LDS dest = wave-uniform base + lane*16
__device__ __forceinline__ void glds16(const void* g, void* l) {
    auto gp = reinterpret_cast<const __attribute__((address_space(1))) uint32_t*>(
        reinterpret_cast<uintptr_t>(g));
    auto lp = reinterpret_cast<__attribute__((address_space(3))) uint32_t*>(
        reinterpret_cast<uintptr_t>(l));
    __builtin_amdgcn_global_load_lds(gp, lp, 16, 0, 0);
}

// ---------------------------------------------------------------------------
// pre_kernel: fused buildA (256 blocks; was 4 blocks = 63 us latency-bound)
// and x -> bf16 conversion (3072 blocks).
// A[mi][pj][s] = sum_r c0[(mi)*32+r] * c1[((r*4+p)*4+j)*64+s], 16384/mat.
// ---------------------------------------------------------------------------
__global__ __launch_bounds__(256) void pre_kernel(TTPtrs P, float* __restrict__ wsA,
                                                  const float* __restrict__ x,
                                                  uint16_t* __restrict__ xb) {
    const int bx = blockIdx.x;
    if (bx < 256) {
        const int mat = bx >> 6;
        const float* c0 = P.c0[mat];
        const float* c1 = P.c1[mat];
        float* A = wsA + mat * 16384;
        int idx = (bx & 63) * 256 + threadIdx.x;
        int s = idx & 63, pj = (idx >> 6) & 15, mi = idx >> 10;
        float acc = 0.f;
        #pragma unroll 8
        for (int r = 0; r < 32; r++)
            acc = fmaf(c0[mi * 32 + r], c1[(r * 16 + pj) * 64 + s], acc);
        A[idx] = acc;
    } else {
        int idx = ((bx - 256) * 256 + threadIdx.x) * 4;
        float4 v = *(const float4*)(x + idx);
        *(uint2*)(xb + idx) = make_uint2(cvtpk(v.x, v.y), cvtpk(v.z, v.w));
    }
}

// Stage B: B[mi][pj][qk][t] = sum_s A * c2, 16*16*36*32 per matrix
__global__ __launch_bounds__(256) void tt_buildB(TTPtrs P, const float* __restrict__ wsA,
                                                 float* __restrict__ wsB) {
    const int mat = blockIdx.y;
    const float* c2 = P.c2[mat];
    const float* A = wsA + mat * 16384;
    float* B = wsB + (size_t)mat * 294912;
    int idx = blockIdx.x * 256 + threadIdx.x;
    int t = idx & 31;
    int rest = idx >> 5;
    int qk = rest % 36;
    int rest2 = rest / 36;
    int pj = rest2 & 15, mi = rest2 >> 4;
    const float* Arow = A + (mi * 16 + pj) * 64;
    float acc = 0.f;
    #pragma unroll 8
    for (int s = 0; s < 64; s++)
        acc = fmaf(Arow[s], c2[(s * 36 + qk) * 32 + t], acc);
    B[idx] = acc;
}

// Stage C: Wbf[mat][out][in] (bf16) = sum_t B * c3.
__global__ __launch_bounds__(256) void tt_buildC(TTPtrs P, const float* __restrict__ wsB,
                                                 uint16_t* __restrict__ Wbf) {
    const int mat = blockIdx.z;
    const float* c3 = P.c3[mat];
    const float* B = wsB + (size_t)mat * 294912;
    uint16_t* Wt = Wbf + (size_t)mat * W_ELEMS;
    int in = blockIdx.x * 256 + threadIdx.x;   // < 768
    int out = blockIdx.y;                      // < 768
    int u = out & 7, q = (out >> 3) % 6, p = (out / 48) & 3, m = out / 192;
    int l = in & 7,  k = (in >> 3) % 6,  j = (in / 48) & 3,  i = in / 192;
    int mi = m * 4 + i, pj = p * 4 + j, qk = q * 6 + k;
    const float* Brow = B + ((size_t)(mi * 16 + pj) * 36 + qk) * 32;
    const float* c3row = c3 + u * 8 + l;
    float acc = 0.f;
    #pragma unroll 8
    for (int t = 0; t < 32; t++)
        acc = fmaf(Brow[t], c3row[t * 64], acc);
    Wt[(size_t)out * D_MODEL + in] = f2bf(acc);
}

// ---------------------------------------------------------------------------
// bf16 MFMA GEMM: Y[row][out] = sum_in X[row][in] * W[out][in] + bias[out]
// 128x128 tile, BK=32, 4 waves, glds staging w/ pre-swizzled source, dbuf LDS,
// one barrier per K-step. MODE 0: f32 out. MODE 1: bf16 out; z==2 writes V
// TRANSPOSED to Vt[b][h][d][s] (packed 8B stores) for scatter-free attn staging.
// ---------------------------------------------------------------------------
template <int MODE>
__global__ __launch_bounds__(256) void gemm_mfma(const uint16_t* __restrict__ X,
                                                 const uint16_t* __restrict__ Wall,
                                                 const float* __restrict__ b0,
                                                 const float* __restrict__ b1,
                                                 const float* __restrict__ b2,
                                                 void* __restrict__ Yall,
                                                 uint16_t* __restrict__ Vt) {
    __shared__ uint16_t lds[2][8192];  // per buf: A tile [0,4096), B tile [4096,8192)
    const int z = blockIdx.z;
    const uint16_t* W = Wall + (size_t)z * W_ELEMS;
    const float* bias = (z == 0) ? b0 : (z == 1 ? b1 : b2);
    const int m0 = blockIdx.x * 128, n0 = blockIdx.y * 128;
    const int tid = threadIdx.x, w = tid >> 6, l = tid & 63;
    const int wr = w >> 1, wc = w & 1;
    const int l15 = l & 15, lg = l >> 4;

    const int srow = w * 32 + (l >> 2);
    const int scol = ((l & 3) ^ ((l >> 2) & 3)) * 8;  // inverse-swizzled source c16
    const uint16_t* Abase = X + (size_t)(m0 + srow) * D_MODEL + scol;
    const uint16_t* Bbase = W + (size_t)(n0 + srow) * D_MODEL + scol;

    f32x4 acc[4][4];
    #pragma unroll
    for (int mi = 0; mi < 4; ++mi)
        #pragma unroll
        for (int ni = 0; ni < 4; ++ni) acc[mi][ni] = (f32x4){0.f, 0.f, 0.f, 0.f};

    auto stage = [&](int buf, int kt) {
        const uint16_t* A0 = Abase + kt * 32;
        const uint16_t* B0 = Bbase + kt * 32;
        glds16(A0, &lds[buf][w * 1024]);
        glds16(A0 + 16 * D_MODEL, &lds[buf][w * 1024 + 512]);
        glds16(B0, &lds[buf][4096 + w * 1024]);
        glds16(B0 + 16 * D_MODEL, &lds[buf][4096 + w * 1024 + 512]);
    };

    stage(0, 0);
    __syncthreads();
    const int roff = ((lg ^ (l & 3)) << 3);
    for (int kt = 0; kt < 24; ++kt) {
        int cur = kt & 1;
        if (kt < 23) stage(cur ^ 1, kt + 1);
        const uint16_t* As = &lds[cur][0];
        const uint16_t* Bs = &lds[cur][4096];
        bf16x8 a[4], bb[4];
        #pragma unroll
        for (int mi = 0; mi < 4; ++mi)
            a[mi] = *(const bf16x8*)(As + (wr * 64 + mi * 16 + l15) * 32 + roff);
        #pragma unroll
        for (int ni = 0; ni < 4; ++ni)
            bb[ni] = *(const bf16x8*)(Bs + (wc * 64 + ni * 16 + l15) * 32 + roff);
        #pragma unroll
        for (int mi = 0; mi < 4; ++mi)
            #pragma unroll
            for (int ni = 0; ni < 4; ++ni)
                acc[mi][ni] = __builtin_amdgcn_mfma_f32_16x16x32_bf16(
                    a[mi], bb[ni], acc[mi][ni], 0, 0, 0);
        __syncthreads();
    }

    float bv[4];
    #pragma unroll
    for (int ni = 0; ni < 4; ++ni) bv[ni] = bias[n0 + wc * 64 + ni * 16 + l15];

    if (MODE == 1 && z == 2) {
        // V^T epilogue: Vt[((b*12+h)*64+d)*2048 + s], 4 consecutive s packed per store
        #pragma unroll
        for (int mi = 0; mi < 4; ++mi) {
            int row = m0 + wr * 64 + mi * 16 + lg * 4;  // token; 4 consecutive
            int bb_ = row >> 11, s = row & 2047;
            #pragma unroll
            for (int ni = 0; ni < 4; ++ni) {
                int col = n0 + wc * 64 + ni * 16 + l15;  // h*64+d
                float v0 = acc[mi][ni][0] + bv[ni], v1 = acc[mi][ni][1] + bv[ni];
                float v2 = acc[mi][ni][2] + bv[ni], v3 = acc[mi][ni][3] + bv[ni];
                *(uint2*)(Vt + ((size_t)(bb_ * 12 + (col >> 6)) * 64 + (col & 63)) * 2048 + s) =
                    make_uint2(cvtpk(v0, v1), cvtpk(v2, v3));
            }
        }
    } else {
        #pragma unroll
        for (int mi = 0; mi < 4; ++mi)
            #pragma unroll
            for (int ni = 0; ni < 4; ++ni)
                #pragma unroll
                for (int r = 0; r < 4; ++r) {
                    int row = m0 + wr * 64 + mi * 16 + lg * 4 + r;
                    int col = n0 + wc * 64 + ni * 16 + l15;
                    float v = acc[mi][ni][r] + bv[ni];
                    if (MODE == 1)
                        ((uint16_t*)Yall + (size_t)z * Y_ELEMS)[(size_t)row * D_MODEL + col] = f2bf(v);
                    else
                        ((float*)Yall)[(size_t)row * D_MODEL + col] = v;
                }
    }
}

// ---------------------------------------------------------------------------
// Causal flash attention, bf16 MFMA. Block = (b,h) x 64 q-rows, 4 waves x 16q.
// Swapped S^T = K*Qs^T. K and V^T both staged via glds (pre-swizzled source)
// into double-buffered LDS; ONE barrier per tile, prefetch issued right after
// the barrier so loads overlap compute. Mask only on diagonal tile; defer-max.
// ---------------------------------------------------------------------------
__global__ __launch_bounds__(256) void attn_mfma(const uint16_t* __restrict__ Q,
                                                 const uint16_t* __restrict__ K,
                                                 const uint16_t* __restrict__ Vt,
                                                 uint16_t* __restrict__ O) {
    __shared__ uint16_t ks[2][4096];   // K tile [64 key][64 d], swizzled
    __shared__ uint16_t vs[2][4096];   // V^T tile [64 d][64 key], swizzled
    __shared__ uint16_t ps[4][1024];   // per-wave P [16 q][64 key], swizzled

    const int bx = blockIdx.x;
    const int qt = 31 - bx / 24;       // big causal tiles scheduled first
    const int bh = bx % 24;
    const int b = bh / 12, h = bh % 12;
    const int tid = threadIdx.x, w = tid >> 6, l = tid & 63;
    const int l15 = l & 15, lg = l >> 4;
    const size_t headoff = (size_t)b * SEQ * D_MODEL + h * 64;
    const size_t vhead = ((size_t)(b * 12 + h)) << 17;   // *64*2048
    const int sc8 = ((l & 7) ^ ((l >> 3) & 7)) * 8;      // pre-swizzled source col
    const int srow = w * 16 + (l >> 3);

    // Q B-frags (col = q, k = d), pre-scaled by 1/8 (exact in bf16)
    bf16x8 qf[2];
    {
        const uint16_t* qp = Q + headoff + (size_t)(qt * 64 + w * 16 + l15) * D_MODEL + lg * 8;
        #pragma unroll
        for (int ds = 0; ds < 2; ++ds) {
            bf16x8 qv = *(const bf16x8*)(qp + ds * 32);
            #pragma unroll
            for (int j = 0; j < 8; ++j)
                qf[ds][j] = (short)f2bf(bf2f((uint16_t)qv[j]) * 0.125f);
        }
    }

    float m_ = -3e38f, l_ = 0.f;
    f32x4 oacc[4];
    #pragma unroll
    for (int ni = 0; ni < 4; ++ni) oacc[ni] = (f32x4){0.f, 0.f, 0.f, 0.f};
    const int qglob = qt * 64 + w * 16 + l15;

    auto stage = [&](int buf, int kt) {
        const uint16_t* ksrc = K + headoff + (size_t)(kt * 64 + srow) * D_MODEL + sc8;
        glds16(ksrc, &ks[buf][w * 1024]);
        glds16(ksrc + 8 * D_MODEL, &ks[buf][w * 1024 + 512]);
        const uint16_t* vsrc = Vt + vhead + (size_t)srow * SEQ + kt * 64 + sc8;
        glds16(vsrc, &vs[buf][w * 1024]);
        glds16(vsrc + 8 * SEQ, &vs[buf][w * 1024 + 512]);
    };

    stage(0, 0);
    for (int kt = 0; kt <= qt; ++kt) {
        const int cur = kt & 1;
        __syncthreads();                       // drains vmcnt -> tile kt staged
        if (kt < qt) stage(cur ^ 1, kt + 1);   // prefetch overlaps compute below

        // S^T[key][q] = K · Qs^T
        f32x4 sacc[4];
        #pragma unroll
        for (int ki = 0; ki < 4; ++ki) sacc[ki] = (f32x4){0.f, 0.f, 0.f, 0.f};
        #pragma unroll
        for (int ds = 0; ds < 2; ++ds)
            #pragma unroll
            for (int ki = 0; ki < 4; ++ki) {
                int byte = (ki * 16 + l15) * 128 + ((((ds << 2) + lg) ^ (l15 & 7)) << 4);
                bf16x8 ak = *(const bf16x8*)((const char*)&ks[cur][0] + byte);
                sacc[ki] = __builtin_amdgcn_mfma_f32_16x16x32_bf16(ak, qf[ds], sacc[ki], 0, 0, 0);
            }

        // online softmax; lane's q = l15, lane holds 16 keys (4 frags x 4 regs)
        const bool diag = (kt == qt);
        float sv[16];
        float mx = -3e38f;
        #pragma unroll
        for (int ki = 0; ki < 4; ++ki)
            #pragma unroll
            for (int r = 0; r < 4; ++r) {
                float s = sacc[ki][r];
                if (diag) {
                    int key = kt * 64 + ki * 16 + lg * 4 + r;
                    if (key > qglob) s = -3e38f;
                }
                sv[ki * 4 + r] = s;
                mx = fmaxf(mx, s);
            }
        mx = fmaxf(mx, __shfl_xor(mx, 16));
        mx = fmaxf(mx, __shfl_xor(mx, 32));
        if (__any(mx > m_ + 8.f)) {            // defer-max (T13): rescale rarely
            float mnew = fmaxf(m_, mx);
            float alpha = __expf(m_ - mnew);
            l_ *= alpha;
            float a0 = __shfl(alpha, lg * 4 + 0), a1 = __shfl(alpha, lg * 4 + 1);
            float a2 = __shfl(alpha, lg * 4 + 2), a3 = __shfl(alpha, lg * 4 + 3);
            #pragma unroll
            for (int ni = 0; ni < 4; ++ni) {
                oacc[ni][0] *= a0; oacc[ni][1] *= a1;
                oacc[ni][2] *= a2; oacc[ni][3] *= a3;
            }
            m_ = mnew;
        }
        float sum = 0.f;
        uint32_t pk[8];
        #pragma unroll
        for (int i = 0; i < 16; i += 2) {
            float p0 = __expf(sv[i] - m_);
            float p1 = __expf(sv[i + 1] - m_);
            sum += p0 + p1;
            pk[i >> 1] = cvtpk(p0, p1);
        }
        sum += __shfl_xor(sum, 16);
        sum += __shfl_xor(sum, 32);
        l_ += sum;

        // write P (4 consecutive keys per b64, swizzled); wave-private region
        uint16_t* psw = &ps[w][0];
        #pragma unroll
        for (int ki = 0; ki < 4; ++ki) {
            int byte = (l15 * 128 + ki * 32 + lg * 8) ^ ((l15 & 7) << 4);
            *(uint2*)((char*)psw + byte) = make_uint2(pk[ki * 2], pk[ki * 2 + 1]);
        }
        asm volatile("s_waitcnt lgkmcnt(0)" ::: "memory");
        __builtin_amdgcn_sched_barrier(0);

        // O[q][d] += P · V
        #pragma unroll
        for (int kss = 0; kss < 2; ++kss) {
            int pbyte = l15 * 128 + ((((kss << 2) + lg) ^ (l15 & 7)) << 4);
            bf16x8 ap = *(const bf16x8*)((const char*)psw + pbyte);
            #pragma unroll
            for (int ni = 0; ni < 4; ++ni) {
                int vbyte = (ni * 16 + l15) * 128 + ((((kss << 2) + lg) ^ (l15 & 7)) << 4);
                bf16x8 bv = *(const bf16x8*)((const char*)&vs[cur][0] + vbyte);
                oacc[ni] = __builtin_amdgcn_mfma_f32_16x16x32_bf16(ap, bv, oacc[ni], 0, 0, 0);
            }
        }
    }

    float li0 = 1.f / __shfl(l_, lg * 4 + 0), li1 = 1.f / __shfl(l_, lg * 4 + 1);
    float li2 = 1.f / __shfl(l_, lg * 4 + 2), li3 = 1.f / __shfl(l_, lg * 4 + 3);
    #pragma unroll
    for (int ni = 0; ni < 4; ++ni) {
        int col = h * 64 + ni * 16 + l15;
        size_t rb = (size_t)(b * SEQ + qt * 64 + w * 16 + lg * 4) * D_MODEL + col;
        O[rb + 0 * D_MODEL] = f2bf(oacc[ni][0] * li0);
        O[rb + 1 * D_MODEL] = f2bf(oacc[ni][1] * li1);
        O[rb + 2 * D_MODEL] = f2bf(oacc[ni][2] * li2);
        O[rb + 3 * D_MODEL] = f2bf(oacc[ni][3] * li3);
    }
}

// ---------------------------------------------------------------------------
// Workspace (bytes):
//   wsA @ 0        262144 fp32 | wsB @ 262144 4718592 fp32
//   Wbf @ 4980736  4718592 bf16 [4][out][in]
//   xbf @ 9699328  6291456 | Qbf @ 15990784 | Kbf @ 22282240 (z*Y_ELEMS from Qbf)
//   Vtbf @ 28573696 (V transposed [2][12][64][2048]) | Obf @ 34865152  ~41.2 MB
// ---------------------------------------------------------------------------
extern "C" void kernel_launch(void* const* d_in, const int* in_sizes, int n_in,
                              void* d_out, int out_size, void* d_ws, size_t ws_size,
                              hipStream_t stream) {
    const float* x = (const float*)d_in[0];
    TTPtrs P;
    const float* biases[4];
    const int base[4] = {2, 7, 12, 17};  // q, k, v, o parameter groups
    for (int t = 0; t < 4; t++) {
        P.c0[t] = (const float*)d_in[base[t] + 0];
        P.c1[t] = (const float*)d_in[base[t] + 1];
        P.c2[t] = (const float*)d_in[base[t] + 2];
        P.c3[t] = (const float*)d_in[base[t] + 3];
        biases[t] = (const float*)d_in[base[t] + 4];
    }

    char* ws = (char*)d_ws;
    float* wsA = (float*)(ws + 0);
    float* wsB = (float*)(ws + 262144);
    uint16_t* Wbf = (uint16_t*)(ws + 4980736);
    uint16_t* xbf = (uint16_t*)(ws + 9699328);
    uint16_t* Qbf = (uint16_t*)(ws + 15990784);
    uint16_t* Kbf = (uint16_t*)(ws + 22282240);
    uint16_t* Vtbf = (uint16_t*)(ws + 28573696);
    uint16_t* Obf = (uint16_t*)(ws + 34865152);
    (void)Kbf;

    pre_kernel<<<dim3(256 + 3072), 256, 0, stream>>>(P, wsA, x, xbf);
    tt_buildB<<<dim3(1152, 4), 256, 0, stream>>>(P, wsA, wsB);
    tt_buildC<<<dim3(3, 768, 4), 256, 0, stream>>>(P, wsB, Wbf);

    // q, k projections (bf16, row-major); v projection written transposed to Vtbf
    gemm_mfma<1><<<dim3(32, 6, 3), 256, 0, stream>>>(xbf, Wbf, biases[0], biases[1],
                                                     biases[2], (void*)Qbf, Vtbf);
    // causal attention (bf16 out)
    attn_mfma<<<dim3(24 * 32), 256, 0, stream>>>(Qbf, Kbf, Vtbf, Obf);

    // output projection (fp32 out -> d_out)
    gemm_mfma<0><<<dim3(32, 6, 1), 256, 0, stream>>>(Obf, Wbf + 3 * (size_t)W_ELEMS,
                                                     biases[3], biases[3], biases[3],
                                                     d_out, nullptr);
}

// Round 5
// 239.773 us; speedup vs baseline: 5.6273x; 1.0153x over previous
//
#include <hip/hip_runtime.h>
#include <cstddef>
#include <cstdint>

// Problem constants
#define D_MODEL 768
#define N_HEADS 12
#define SEQ 2048
#define BATCH 2
#define NROWS (BATCH * SEQ)          // 4096
#define W_ELEMS (D_MODEL * D_MODEL)  // 589824
#define Y_ELEMS (NROWS * D_MODEL)    // 3145728

typedef __attribute__((ext_vector_type(8))) short bf16x8;
typedef __attribute__((ext_vector_type(4))) float f32x4;

struct TTPtrs {
    const float* c0[4];
    const float* c1[4];
    const float* c2[4];
    const float* c3[4];
};

__device__ __forceinline__ float bf2f(uint16_t u) {
    union { uint32_t u; float f; } c; c.u = ((uint32_t)u) << 16; return c.f;
}
__device__ __forceinline__ uint16_t f2bf(float f) {
    union { float f; uint32_t u; } c; c.f = f;
    uint32_t x = c.u + 0x7fffu + ((c.u >> 16) & 1u);   // RNE
    return (uint16_t)(x >> 16);
}
// pack two f32 -> 2x bf16 in one VALU op (T12 recipe; no builtin on gfx950)
__device__ __forceinline__ uint32_t cvtpk(float lo, float hi) {
    uint32_t r;
    asm("v_cvt_pk_bf16_f32 %0, %1, %2" : "=v"(r) : "v"(lo), "v"(hi));
    return r;
}
// global->LDS direct copy, 16B per lane; LDS dest = wave-uniform base + lane*16
__device__ __forceinline__ void glds16(const void* g, void* l) {
    auto gp = reinterpret_cast<const __attribute__((address_space(1))) uint32_t*>(
        reinterpret_cast<uintptr_t>(g));
    auto lp = reinterpret_cast<__attribute__((address_space(3))) uint32_t*>(
        reinterpret_cast<uintptr_t>(l));
    __builtin_amdgcn_global_load_lds(gp, lp, 16, 0, 0);
}

// ---------------------------------------------------------------------------
// pre_kernel: fused buildA (256 blocks) and x -> bf16 conversion (3072 blocks).
// A[mi][pj][s] = sum_r c0[mi*32+r] * c1[(r*16+pj)*64+s], 16384/mat.
// ---------------------------------------------------------------------------
__global__ __launch_bounds__(256) void pre_kernel(TTPtrs P, float* __restrict__ wsA,
                                                  const float* __restrict__ x,
                                                  uint16_t* __restrict__ xb) {
    const int bx = blockIdx.x;
    if (bx < 256) {
        const int mat = bx >> 6;
        const float* c0 = P.c0[mat];
        const float* c1 = P.c1[mat];
        float* A = wsA + mat * 16384;
        int idx = (bx & 63) * 256 + threadIdx.x;
        int s = idx & 63, pj = (idx >> 6) & 15, mi = idx >> 10;
        float acc = 0.f;
        #pragma unroll 8
        for (int r = 0; r < 32; r++)
            acc = fmaf(c0[mi * 32 + r], c1[(r * 16 + pj) * 64 + s], acc);
        A[idx] = acc;
    } else {
        int idx = ((bx - 256) * 256 + threadIdx.x) * 4;
        float4 v = *(const float4*)(x + idx);
        *(uint2*)(xb + idx) = make_uint2(cvtpk(v.x, v.y), cvtpk(v.z, v.w));
    }
}

// Stage B: B[mi][pj][qk][t] = sum_s A * c2, 16*16*36*32 per matrix
__global__ __launch_bounds__(256) void tt_buildB(TTPtrs P, const float* __restrict__ wsA,
                                                 float* __restrict__ wsB) {
    const int mat = blockIdx.y;
    const float* c2 = P.c2[mat];
    const float* A = wsA + mat * 16384;
    float* B = wsB + (size_t)mat * 294912;
    int idx = blockIdx.x * 256 + threadIdx.x;
    int t = idx & 31;
    int rest = idx >> 5;
    int qk = rest % 36;
    int rest2 = rest / 36;
    int pj = rest2 & 15, mi = rest2 >> 4;
    const float* Arow = A + (mi * 16 + pj) * 64;
    float acc = 0.f;
    #pragma unroll 8
    for (int s = 0; s < 64; s++)
        acc = fmaf(Arow[s], c2[(s * 36 + qk) * 32 + t], acc);
    B[idx] = acc;
}

// ---------------------------------------------------------------------------
// Stage C (LDS rewrite; old version read B/c3 per-thread-sequential =
// uncoalesced 4B loads, latency-bound). Block = one (mat, mi, pj):
// stages B[mi,pj][36][32] (coalesced, padded stride 33) + full c3 [32][64]
// into LDS, computes the 48x48 (qu x kl) output patch, 9 outputs/thread.
// Wbf[mat][out][in], out=((m*4+p)*6+q)*8+u, in=((i*4+j)*6+k)*8+l.
// ---------------------------------------------------------------------------
__global__ __launch_bounds__(256) void tt_buildC(TTPtrs P, const float* __restrict__ wsB,
                                                 uint16_t* __restrict__ Wbf) {
    __shared__ float b_lds[36 * 33];   // [qk][t], stride 33 -> conflict-free
    __shared__ float c_lds[32 * 64];   // [t][ul]
    const int mat = blockIdx.y;
    const int mipj = blockIdx.x;       // mi*16 + pj
    const int mi = mipj >> 4, pj = mipj & 15;
    const int m = mi >> 2, i = mi & 3, p = pj >> 2, j = pj & 3;
    const float* Bsrc = wsB + (size_t)mat * 294912 + (size_t)mipj * 1152;
    const float* c3 = P.c3[mat];
    uint16_t* Wt = Wbf + (size_t)mat * W_ELEMS;
    const int tid = threadIdx.x;

    for (int e = tid; e < 1152; e += 256) {
        int qk = e >> 5, t = e & 31;
        b_lds[qk * 33 + t] = Bsrc[e];
    }
    for (int e = tid; e < 2048; e += 256)
        c_lds[e] = c3[e];
    __syncthreads();

    const int outbase = (m * 4 + p) * 48;      // + q*8 + u
    const int inbase = (i * 4 + j) * 48;       // + k*8 + l
    #pragma unroll
    for (int n = 0; n < 9; n++) {
        int idx = n * 256 + tid;               // < 2304
        int qu = idx / 48, kl = idx % 48;
        int q = qu >> 3, u = qu & 7, k = kl >> 3, l = kl & 7;
        const float* brow = &b_lds[(q * 6 + k) * 33];
        const float* crow = &c_lds[u * 8 + l];
        float acc = 0.f;
        #pragma unroll 8
        for (int t = 0; t < 32; t++)
            acc = fmaf(brow[t], crow[t * 64], acc);
        Wt[(size_t)(outbase + qu) * D_MODEL + inbase + kl] = f2bf(acc);
    }
}

// ---------------------------------------------------------------------------
// bf16 MFMA GEMM: Y[row][out] = sum_in X[row][in] * W[out][in] + bias[out]
// 128x128 tile, BK=32, 4 waves, glds staging w/ pre-swizzled source, dbuf LDS,
// one barrier per K-step. MODE 0: f32 out. MODE 1: bf16 out; z==2 writes V
// TRANSPOSED to Vt[b][h][d][s] (packed 8B stores) for scatter-free attn staging.
// ---------------------------------------------------------------------------
template <int MODE>
__global__ __launch_bounds__(256) void gemm_mfma(const uint16_t* __restrict__ X,
                                                 const uint16_t* __restrict__ Wall,
                                                 const float* __restrict__ b0,
                                                 const float* __restrict__ b1,
                                                 const float* __restrict__ b2,
                                                 void* __restrict__ Yall,
                                                 uint16_t* __restrict__ Vt) {
    __shared__ uint16_t lds[2][8192];  // per buf: A tile [0,4096), B tile [4096,8192)
    const int z = blockIdx.z;
    const uint16_t* W = Wall + (size_t)z * W_ELEMS;
    const float* bias = (z == 0) ? b0 : (z == 1 ? b1 : b2);
    const int m0 = blockIdx.x * 128, n0 = blockIdx.y * 128;
    const int tid = threadIdx.x, w = tid >> 6, l = tid & 63;
    const int wr = w >> 1, wc = w & 1;
    const int l15 = l & 15, lg = l >> 4;

    const int srow = w * 32 + (l >> 2);
    const int scol = ((l & 3) ^ ((l >> 2) & 3)) * 8;  // inverse-swizzled source c16
    const uint16_t* Abase = X + (size_t)(m0 + srow) * D_MODEL + scol;
    const uint16_t* Bbase = W + (size_t)(n0 + srow) * D_MODEL + scol;

    f32x4 acc[4][4];
    #pragma unroll
    for (int mi = 0; mi < 4; ++mi)
        #pragma unroll
        for (int ni = 0; ni < 4; ++ni) acc[mi][ni] = (f32x4){0.f, 0.f, 0.f, 0.f};

    auto stage = [&](int buf, int kt) {
        const uint16_t* A0 = Abase + kt * 32;
        const uint16_t* B0 = Bbase + kt * 32;
        glds16(A0, &lds[buf][w * 1024]);
        glds16(A0 + 16 * D_MODEL, &lds[buf][w * 1024 + 512]);
        glds16(B0, &lds[buf][4096 + w * 1024]);
        glds16(B0 + 16 * D_MODEL, &lds[buf][4096 + w * 1024 + 512]);
    };

    stage(0, 0);
    __syncthreads();
    const int roff = ((lg ^ (l & 3)) << 3);
    for (int kt = 0; kt < 24; ++kt) {
        int cur = kt & 1;
        if (kt < 23) stage(cur ^ 1, kt + 1);
        const uint16_t* As = &lds[cur][0];
        const uint16_t* Bs = &lds[cur][4096];
        bf16x8 a[4], bb[4];
        #pragma unroll
        for (int mi = 0; mi < 4; ++mi)
            a[mi] = *(const bf16x8*)(As + (wr * 64 + mi * 16 + l15) * 32 + roff);
        #pragma unroll
        for (int ni = 0; ni < 4; ++ni)
            bb[ni] = *(const bf16x8*)(Bs + (wc * 64 + ni * 16 + l15) * 32 + roff);
        #pragma unroll
        for (int mi = 0; mi < 4; ++mi)
            #pragma unroll
            for (int ni = 0; ni < 4; ++ni)
                acc[mi][ni] = __builtin_amdgcn_mfma_f32_16x16x32_bf16(
                    a[mi], bb[ni], acc[mi][ni], 0, 0, 0);
        __syncthreads();
    }

    float bv[4];
    #pragma unroll
    for (int ni = 0; ni < 4; ++ni) bv[ni] = bias[n0 + wc * 64 + ni * 16 + l15];

    if (MODE == 1 && z == 2) {
        // V^T epilogue: Vt[((b*12+h)*64+d)*2048 + s], 4 consecutive s packed per store
        #pragma unroll
        for (int mi = 0; mi < 4; ++mi) {
            int row = m0 + wr * 64 + mi * 16 + lg * 4;  // token; 4 consecutive
            int bb_ = row >> 11, s = row & 2047;
            #pragma unroll
            for (int ni = 0; ni < 4; ++ni) {
                int col = n0 + wc * 64 + ni * 16 + l15;  // h*64+d
                float v0 = acc[mi][ni][0] + bv[ni], v1 = acc[mi][ni][1] + bv[ni];
                float v2 = acc[mi][ni][2] + bv[ni], v3 = acc[mi][ni][3] + bv[ni];
                *(uint2*)(Vt + ((size_t)(bb_ * 12 + (col >> 6)) * 64 + (col & 63)) * 2048 + s) =
                    make_uint2(cvtpk(v0, v1), cvtpk(v2, v3));
            }
        }
    } else {
        #pragma unroll
        for (int mi = 0; mi < 4; ++mi)
            #pragma unroll
            for (int ni = 0; ni < 4; ++ni)
                #pragma unroll
                for (int r = 0; r < 4; ++r) {
                    int row = m0 + wr * 64 + mi * 16 + lg * 4 + r;
                    int col = n0 + wc * 64 + ni * 16 + l15;
                    float v = acc[mi][ni][r] + bv[ni];
                    if (MODE == 1)
                        ((uint16_t*)Yall + (size_t)z * Y_ELEMS)[(size_t)row * D_MODEL + col] = f2bf(v);
                    else
                        ((float*)Yall)[(size_t)row * D_MODEL + col] = v;
                }
    }
}

// ---------------------------------------------------------------------------
// Causal flash attention, bf16 MFMA. Block = (b,h) x 64 q-rows, 4 waves x 16q.
// Swapped S^T = K*Qs^T. Q pre-scaled by log2(e)/8 so softmax is raw v_exp_f32
// (exp2 domain). K and V^T staged via glds into dbuf LDS; one barrier/tile,
// prefetch-after-barrier. Diagonal-only masking; defer-max (T13, log2 units);
// s_setprio around MFMA clusters (T5).
// ---------------------------------------------------------------------------
__global__ __launch_bounds__(256) void attn_mfma(const uint16_t* __restrict__ Q,
                                                 const uint16_t* __restrict__ K,
                                                 const uint16_t* __restrict__ Vt,
                                                 uint16_t* __restrict__ O) {
    __shared__ uint16_t ks[2][4096];   // K tile [64 key][64 d], swizzled
    __shared__ uint16_t vs[2][4096];   // V^T tile [64 d][64 key], swizzled
    __shared__ uint16_t ps[4][1024];   // per-wave P [16 q][64 key], swizzled

    const int bx = blockIdx.x;
    const int qt = 31 - bx / 24;       // big causal tiles scheduled first
    const int bh = bx % 24;
    const int b = bh / 12, h = bh % 12;
    const int tid = threadIdx.x, w = tid >> 6, l = tid & 63;
    const int l15 = l & 15, lg = l >> 4;
    const size_t headoff = (size_t)b * SEQ * D_MODEL + h * 64;
    const size_t vhead = ((size_t)(b * 12 + h)) << 17;   // *64*2048
    const int sc8 = ((l & 7) ^ ((l >> 3) & 7)) * 8;      // pre-swizzled source col
    const int srow = w * 16 + (l >> 3);

    // Q B-frags (col = q, k = d), pre-scaled by log2(e)/8 (exp2-domain scores)
    const float QS = 0.125f * 1.44269504088896f;
    bf16x8 qf[2];
    {
        const uint16_t* qp = Q + headoff + (size_t)(qt * 64 + w * 16 + l15) * D_MODEL + lg * 8;
        #pragma unroll
        for (int ds = 0; ds < 2; ++ds) {
            bf16x8 qv = *(const bf16x8*)(qp + ds * 32);
            #pragma unroll
            for (int j = 0; j < 8; ++j)
                qf[ds][j] = (short)f2bf(bf2f((uint16_t)qv[j]) * QS);
        }
    }

    float m_ = -3e38f, l_ = 0.f;
    f32x4 oacc[4];
    #pragma unroll
    for (int ni = 0; ni < 4; ++ni) oacc[ni] = (f32x4){0.f, 0.f, 0.f, 0.f};
    const int qglob = qt * 64 + w * 16 + l15;

    auto stage = [&](int buf, int kt) {
        const uint16_t* ksrc = K + headoff + (size_t)(kt * 64 + srow) * D_MODEL + sc8;
        glds16(ksrc, &ks[buf][w * 1024]);
        glds16(ksrc + 8 * D_MODEL, &ks[buf][w * 1024 + 512]);
        const uint16_t* vsrc = Vt + vhead + (size_t)srow * SEQ + kt * 64 + sc8;
        glds16(vsrc, &vs[buf][w * 1024]);
        glds16(vsrc + 8 * SEQ, &vs[buf][w * 1024 + 512]);
    };

    stage(0, 0);
    for (int kt = 0; kt <= qt; ++kt) {
        const int cur = kt & 1;
        __syncthreads();                       // drains vmcnt -> tile kt staged
        if (kt < qt) stage(cur ^ 1, kt + 1);   // prefetch overlaps compute below

        // S^T[key][q] = K · Qs^T   (exp2-domain logits)
        f32x4 sacc[4];
        #pragma unroll
        for (int ki = 0; ki < 4; ++ki) sacc[ki] = (f32x4){0.f, 0.f, 0.f, 0.f};
        __builtin_amdgcn_s_setprio(1);
        #pragma unroll
        for (int ds = 0; ds < 2; ++ds)
            #pragma unroll
            for (int ki = 0; ki < 4; ++ki) {
                int byte = (ki * 16 + l15) * 128 + ((((ds << 2) + lg) ^ (l15 & 7)) << 4);
                bf16x8 ak = *(const bf16x8*)((const char*)&ks[cur][0] + byte);
                sacc[ki] = __builtin_amdgcn_mfma_f32_16x16x32_bf16(ak, qf[ds], sacc[ki], 0, 0, 0);
            }
        __builtin_amdgcn_s_setprio(0);

        // online softmax (log2 domain); lane's q = l15, lane holds 16 keys
        const bool diag = (kt == qt);
        float sv[16];
        float mx = -3e38f;
        #pragma unroll
        for (int ki = 0; ki < 4; ++ki)
            #pragma unroll
            for (int r = 0; r < 4; ++r) {
                float s = sacc[ki][r];
                if (diag) {
                    int key = kt * 64 + ki * 16 + lg * 4 + r;
                    if (key > qglob) s = -3e38f;
                }
                sv[ki * 4 + r] = s;
                mx = fmaxf(mx, s);
            }
        mx = fmaxf(mx, __shfl_xor(mx, 16));
        mx = fmaxf(mx, __shfl_xor(mx, 32));
        if (__any(mx > m_ + 11.54f)) {         // defer-max (T13), 8 nats in log2
            float mnew = fmaxf(m_, mx);
            float alpha = __builtin_amdgcn_exp2f(m_ - mnew);
            l_ *= alpha;
            float a0 = __shfl(alpha, lg * 4 + 0), a1 = __shfl(alpha, lg * 4 + 1);
            float a2 = __shfl(alpha, lg * 4 + 2), a3 = __shfl(alpha, lg * 4 + 3);
            #pragma unroll
            for (int ni = 0; ni < 4; ++ni) {
                oacc[ni][0] *= a0; oacc[ni][1] *= a1;
                oacc[ni][2] *= a2; oacc[ni][3] *= a3;
            }
            m_ = mnew;
        }
        float sum = 0.f;
        uint32_t pk[8];
        #pragma unroll
        for (int i = 0; i < 16; i += 2) {
            float p0 = __builtin_amdgcn_exp2f(sv[i] - m_);
            float p1 = __builtin_amdgcn_exp2f(sv[i + 1] - m_);
            sum += p0 + p1;
            pk[i >> 1] = cvtpk(p0, p1);
        }
        sum += __shfl_xor(sum, 16);
        sum += __shfl_xor(sum, 32);
        l_ += sum;

        // write P (4 consecutive keys per b64, swizzled); wave-private region
        uint16_t* psw = &ps[w][0];
        #pragma unroll
        for (int ki = 0; ki < 4; ++ki) {
            int byte = (l15 * 128 + ki * 32 + lg * 8) ^ ((l15 & 7) << 4);
            *(uint2*)((char*)psw + byte) = make_uint2(pk[ki * 2], pk[ki * 2 + 1]);
        }
        asm volatile("s_waitcnt lgkmcnt(0)" ::: "memory");
        __builtin_amdgcn_sched_barrier(0);

        // O[q][d] += P · V
        __builtin_amdgcn_s_setprio(1);
        #pragma unroll
        for (int kss = 0; kss < 2; ++kss) {
            int pbyte = l15 * 128 + ((((kss << 2) + lg) ^ (l15 & 7)) << 4);
            bf16x8 ap = *(const bf16x8*)((const char*)psw + pbyte);
            #pragma unroll
            for (int ni = 0; ni < 4; ++ni) {
                int vbyte = (ni * 16 + l15) * 128 + ((((kss << 2) + lg) ^ (l15 & 7)) << 4);
                bf16x8 bv = *(const bf16x8*)((const char*)&vs[cur][0] + vbyte);
                oacc[ni] = __builtin_amdgcn_mfma_f32_16x16x32_bf16(ap, bv, oacc[ni], 0, 0, 0);
            }
        }
        __builtin_amdgcn_s_setprio(0);
    }

    float li0 = 1.f / __shfl(l_, lg * 4 + 0), li1 = 1.f / __shfl(l_, lg * 4 + 1);
    float li2 = 1.f / __shfl(l_, lg * 4 + 2), li3 = 1.f / __shfl(l_, lg * 4 + 3);
    #pragma unroll
    for (int ni = 0; ni < 4; ++ni) {
        int col = h * 64 + ni * 16 + l15;
        size_t rb = (size_t)(b * SEQ + qt * 64 + w * 16 + lg * 4) * D_MODEL + col;
        O[rb + 0 * D_MODEL] = f2bf(oacc[ni][0] * li0);
        O[rb + 1 * D_MODEL] = f2bf(oacc[ni][1] * li1);
        O[rb + 2 * D_MODEL] = f2bf(oacc[ni][2] * li2);
        O[rb + 3 * D_MODEL] = f2bf(oacc[ni][3] * li3);
    }
}

// ---------------------------------------------------------------------------
// Workspace (bytes):
//   wsA @ 0        262144 fp32 | wsB @ 262144 4718592 fp32
//   Wbf @ 4980736  4718592 bf16 [4][out][in]
//   xbf @ 9699328  6291456 | Qbf @ 15990784 | Kbf @ 22282240 (z*Y_ELEMS from Qbf)
//   Vtbf @ 28573696 (V transposed [2][12][64][2048]) | Obf @ 34865152  ~41.2 MB
// ---------------------------------------------------------------------------
extern "C" void kernel_launch(void* const* d_in, const int* in_sizes, int n_in,
                              void* d_out, int out_size, void* d_ws, size_t ws_size,
                              hipStream_t stream) {
    const float* x = (const float*)d_in[0];
    TTPtrs P;
    const float* biases[4];
    const int base[4] = {2, 7, 12, 17};  // q, k, v, o parameter groups
    for (int t = 0; t < 4; t++) {
        P.c0[t] = (const float*)d_in[base[t] + 0];
        P.c1[t] = (const float*)d_in[base[t] + 1];
        P.c2[t] = (const float*)d_in[base[t] + 2];
        P.c3[t] = (const float*)d_in[base[t] + 3];
        biases[t] = (const float*)d_in[base[t] + 4];
    }

    char* ws = (char*)d_ws;
    float* wsA = (float*)(ws + 0);
    float* wsB = (float*)(ws + 262144);
    uint16_t* Wbf = (uint16_t*)(ws + 4980736);
    uint16_t* xbf = (uint16_t*)(ws + 9699328);
    uint16_t* Qbf = (uint16_t*)(ws + 15990784);
    uint16_t* Kbf = (uint16_t*)(ws + 22282240);
    uint16_t* Vtbf = (uint16_t*)(ws + 28573696);
    uint16_t* Obf = (uint16_t*)(ws + 34865152);
    (void)Kbf;

    pre_kernel<<<dim3(256 + 3072), 256, 0, stream>>>(P, wsA, x, xbf);
    tt_buildB<<<dim3(1152, 4), 256, 0, stream>>>(P, wsA, wsB);
    tt_buildC<<<dim3(256, 4), 256, 0, stream>>>(P, wsB, Wbf);

    // q, k projections (bf16, row-major); v projection written transposed to Vtbf
    gemm_mfma<1><<<dim3(32, 6, 3), 256, 0, stream>>>(xbf, Wbf, biases[0], biases[1],
                                                     biases[2], (void*)Qbf, Vtbf);
    // causal attention (bf16 out)
    attn_mfma<<<dim3(24 * 32), 256, 0, stream>>>(Qbf, Kbf, Vtbf, Obf);

    // output projection (fp32 out -> d_out)
    gemm_mfma<0><<<dim3(32, 6, 1), 256, 0, stream>>>(Obf, Wbf + 3 * (size_t)W_ELEMS,
                                                     biases[3], biases[3], biases[3],
                                                     d_out, nullptr);
}

// Round 7
// 237.457 us; speedup vs baseline: 5.6822x; 1.0098x over previous
//
#include <hip/hip_runtime.h>
#include <cstddef>
#include <cstdint>

// Problem constants
#define D_MODEL 768
#define N_HEADS 12
#define SEQ 2048
#define BATCH 2
#define NROWS (BATCH * SEQ)          // 4096
#define W_ELEMS (D_MODEL * D_MODEL)  // 589824
#define Y_ELEMS (NROWS * D_MODEL)    // 3145728

typedef __attribute__((ext_vector_type(8))) short bf16x8;
typedef __attribute__((ext_vector_type(4))) float f32x4;

struct TTPtrs {
    const float* c0[4];
    const float* c1[4];
    const float* c2[4];
    const float* c3[4];
};

__device__ __forceinline__ float bf2f(uint16_t u) {
    union { uint32_t u; float f; } c; c.u = ((uint32_t)u) << 16; return c.f;
}
__device__ __forceinline__ uint16_t f2bf(float f) {
    union { float f; uint32_t u; } c; c.f = f;
    uint32_t x = c.u + 0x7fffu + ((c.u >> 16) & 1u);   // RNE
    return (uint16_t)(x >> 16);
}
__device__ __forceinline__ uint32_t cvtpk(float lo, float hi) {
    uint32_t r;
    asm("v_cvt_pk_bf16_f32 %0, %1, %2" : "=v"(r) : "v"(lo), "v"(hi));
    return r;
}
__device__ __forceinline__ void glds16(const void* g, void* l) {
    auto gp = reinterpret_cast<const __attribute__((address_space(1))) uint32_t*>(
        reinterpret_cast<uintptr_t>(g));
    auto lp = reinterpret_cast<__attribute__((address_space(3))) uint32_t*>(
        reinterpret_cast<uintptr_t>(l));
    __builtin_amdgcn_global_load_lds(gp, lp, 16, 0, 0);
}

// ---------------------------------------------------------------------------
// pre_kernel: fused buildA (256 blocks) and x -> bf16 conversion (3072 blocks).
// ---------------------------------------------------------------------------
__global__ __launch_bounds__(256) void pre_kernel(TTPtrs P, float* __restrict__ wsA,
                                                  const float* __restrict__ x,
                                                  uint16_t* __restrict__ xb) {
    const int bx = blockIdx.x;
    if (bx < 256) {
        const int mat = bx >> 6;
        const float* c0 = P.c0[mat];
        const float* c1 = P.c1[mat];
        float* A = wsA + mat * 16384;
        int idx = (bx & 63) * 256 + threadIdx.x;
        int s = idx & 63, pj = (idx >> 6) & 15, mi = idx >> 10;
        float acc = 0.f;
        #pragma unroll 8
        for (int r = 0; r < 32; r++)
            acc = fmaf(c0[mi * 32 + r], c1[(r * 16 + pj) * 64 + s], acc);
        A[idx] = acc;
    } else {
        int idx = ((bx - 256) * 256 + threadIdx.x) * 4;
        float4 v = *(const float4*)(x + idx);
        *(uint2*)(xb + idx) = make_uint2(cvtpk(v.x, v.y), cvtpk(v.z, v.w));
    }
}

// Stage B: B[mi][pj][qk][t] = sum_s A * c2, 16*16*36*32 per matrix
__global__ __launch_bounds__(256) void tt_buildB(TTPtrs P, const float* __restrict__ wsA,
                                                 float* __restrict__ wsB) {
    const int mat = blockIdx.y;
    const float* c2 = P.c2[mat];
    const float* A = wsA + mat * 16384;
    float* B = wsB + (size_t)mat * 294912;
    int idx = blockIdx.x * 256 + threadIdx.x;
    int t = idx & 31;
    int rest = idx >> 5;
    int qk = rest % 36;
    int rest2 = rest / 36;
    int pj = rest2 & 15, mi = rest2 >> 4;
    const float* Arow = A + (mi * 16 + pj) * 64;
    float acc = 0.f;
    #pragma unroll 8
    for (int s = 0; s < 64; s++)
        acc = fmaf(Arow[s], c2[(s * 36 + qk) * 32 + t], acc);
    B[idx] = acc;
}

// Stage C: LDS-staged; block = one (mat, mi, pj); 9 outputs/thread.
__global__ __launch_bounds__(256) void tt_buildC(TTPtrs P, const float* __restrict__ wsB,
                                                 uint16_t* __restrict__ Wbf) {
    __shared__ float b_lds[36 * 33];
    __shared__ float c_lds[32 * 64];
    const int mat = blockIdx.y;
    const int mipj = blockIdx.x;
    const int mi = mipj >> 4, pj = mipj & 15;
    const int m = mi >> 2, i = mi & 3, p = pj >> 2, j = pj & 3;
    const float* Bsrc = wsB + (size_t)mat * 294912 + (size_t)mipj * 1152;
    const float* c3 = P.c3[mat];
    uint16_t* Wt = Wbf + (size_t)mat * W_ELEMS;
    const int tid = threadIdx.x;

    for (int e = tid; e < 1152; e += 256) {
        int qk = e >> 5, t = e & 31;
        b_lds[qk * 33 + t] = Bsrc[e];
    }
    for (int e = tid; e < 2048; e += 256)
        c_lds[e] = c3[e];
    __syncthreads();

    const int outbase = (m * 4 + p) * 48;
    const int inbase = (i * 4 + j) * 48;
    #pragma unroll
    for (int n = 0; n < 9; n++) {
        int idx = n * 256 + tid;
        int qu = idx / 48, kl = idx % 48;
        int q = qu >> 3, u = qu & 7, k = kl >> 3, l = kl & 7;
        const float* brow = &b_lds[(q * 6 + k) * 33];
        const float* crow = &c_lds[u * 8 + l];
        float acc = 0.f;
        #pragma unroll 8
        for (int t = 0; t < 32; t++)
            acc = fmaf(brow[t], crow[t * 64], acc);
        Wt[(size_t)(outbase + qu) * D_MODEL + inbase + kl] = f2bf(acc);
    }
}

// ---------------------------------------------------------------------------
// bf16 MFMA GEMM (unchanged structure). MODE 0: f32 out. MODE 1: bf16 out;
// z==2 writes V transposed to Vt[b][h][d][s].
// ---------------------------------------------------------------------------
template <int MODE>
__global__ __launch_bounds__(256) void gemm_mfma(const uint16_t* __restrict__ X,
                                                 const uint16_t* __restrict__ Wall,
                                                 const float* __restrict__ b0,
                                                 const float* __restrict__ b1,
                                                 const float* __restrict__ b2,
                                                 void* __restrict__ Yall,
                                                 uint16_t* __restrict__ Vt) {
    __shared__ uint16_t lds[2][8192];
    const int z = blockIdx.z;
    const uint16_t* W = Wall + (size_t)z * W_ELEMS;
    const float* bias = (z == 0) ? b0 : (z == 1 ? b1 : b2);
    const int m0 = blockIdx.x * 128, n0 = blockIdx.y * 128;
    const int tid = threadIdx.x, w = tid >> 6, l = tid & 63;
    const int wr = w >> 1, wc = w & 1;
    const int l15 = l & 15, lg = l >> 4;

    const int srow = w * 32 + (l >> 2);
    const int scol = ((l & 3) ^ ((l >> 2) & 3)) * 8;
    const uint16_t* Abase = X + (size_t)(m0 + srow) * D_MODEL + scol;
    const uint16_t* Bbase = W + (size_t)(n0 + srow) * D_MODEL + scol;

    f32x4 acc[4][4];
    #pragma unroll
    for (int mi = 0; mi < 4; ++mi)
        #pragma unroll
        for (int ni = 0; ni < 4; ++ni) acc[mi][ni] = (f32x4){0.f, 0.f, 0.f, 0.f};

    auto stage = [&](int buf, int kt) {
        const uint16_t* A0 = Abase + kt * 32;
        const uint16_t* B0 = Bbase + kt * 32;
        glds16(A0, &lds[buf][w * 1024]);
        glds16(A0 + 16 * D_MODEL, &lds[buf][w * 1024 + 512]);
        glds16(B0, &lds[buf][4096 + w * 1024]);
        glds16(B0 + 16 * D_MODEL, &lds[buf][4096 + w * 1024 + 512]);
    };

    stage(0, 0);
    __syncthreads();
    const int roff = ((lg ^ (l & 3)) << 3);
    for (int kt = 0; kt < 24; ++kt) {
        int cur = kt & 1;
        if (kt < 23) stage(cur ^ 1, kt + 1);
        const uint16_t* As = &lds[cur][0];
        const uint16_t* Bs = &lds[cur][4096];
        bf16x8 a[4], bb[4];
        #pragma unroll
        for (int mi = 0; mi < 4; ++mi)
            a[mi] = *(const bf16x8*)(As + (wr * 64 + mi * 16 + l15) * 32 + roff);
        #pragma unroll
        for (int ni = 0; ni < 4; ++ni)
            bb[ni] = *(const bf16x8*)(Bs + (wc * 64 + ni * 16 + l15) * 32 + roff);
        #pragma unroll
        for (int mi = 0; mi < 4; ++mi)
            #pragma unroll
            for (int ni = 0; ni < 4; ++ni)
                acc[mi][ni] = __builtin_amdgcn_mfma_f32_16x16x32_bf16(
                    a[mi], bb[ni], acc[mi][ni], 0, 0, 0);
        __syncthreads();
    }

    float bv[4];
    #pragma unroll
    for (int ni = 0; ni < 4; ++ni) bv[ni] = bias[n0 + wc * 64 + ni * 16 + l15];

    if (MODE == 1 && z == 2) {
        #pragma unroll
        for (int mi = 0; mi < 4; ++mi) {
            int row = m0 + wr * 64 + mi * 16 + lg * 4;
            int bb_ = row >> 11, s = row & 2047;
            #pragma unroll
            for (int ni = 0; ni < 4; ++ni) {
                int col = n0 + wc * 64 + ni * 16 + l15;
                float v0 = acc[mi][ni][0] + bv[ni], v1 = acc[mi][ni][1] + bv[ni];
                float v2 = acc[mi][ni][2] + bv[ni], v3 = acc[mi][ni][3] + bv[ni];
                *(uint2*)(Vt + ((size_t)(bb_ * 12 + (col >> 6)) * 64 + (col & 63)) * 2048 + s) =
                    make_uint2(cvtpk(v0, v1), cvtpk(v2, v3));
            }
        }
    } else {
        #pragma unroll
        for (int mi = 0; mi < 4; ++mi)
            #pragma unroll
            for (int ni = 0; ni < 4; ++ni)
                #pragma unroll
                for (int r = 0; r < 4; ++r) {
                    int row = m0 + wr * 64 + mi * 16 + lg * 4 + r;
                    int col = n0 + wc * 64 + ni * 16 + l15;
                    float v = acc[mi][ni][r] + bv[ni];
                    if (MODE == 1)
                        ((uint16_t*)Yall + (size_t)z * Y_ELEMS)[(size_t)row * D_MODEL + col] = f2bf(v);
                    else
                        ((float*)Yall)[(size_t)row * D_MODEL + col] = v;
                }
    }
}

// ---------------------------------------------------------------------------
// Chunked causal flash attention (key-split for load balance).
// Block bx (0..1919): u = bx/24 selects (qt, chunk) via the schedule below
// (big chunks first), bh = bx%24. Chunk = up to 8 key-tiles (512 keys).
// Writes NORMALIZED partial O (bf16) + per-q combine weight t = m + log2(l).
// Per-bh units: qt=24..31 have 4 chunks, 16..23: 3, 8..15: 2, 0..7: 1 -> 80.
// ---------------------------------------------------------------------------
__global__ __launch_bounds__(256) void attn_mfma(const uint16_t* __restrict__ Q,
                                                 const uint16_t* __restrict__ K,
                                                 const uint16_t* __restrict__ Vt,
                                                 uint16_t* __restrict__ pO1,
                                                 uint16_t* __restrict__ pO2,
                                                 float* __restrict__ tbuf) {
    __shared__ uint16_t ks[2][4096];
    __shared__ uint16_t vs[2][4096];
    __shared__ uint16_t ps[4][1024];

    const int bx = blockIdx.x;
    const int u = bx / 24;
    const int bh = bx % 24;
    int g, c;
    if (u < 32)      { g = u >> 2,            c = u & 3; }
    else if (u < 56) { int t = u - 32; g = 8 + t / 3,  c = t % 3; }
    else if (u < 72) { int t = u - 56; g = 16 + (t >> 1), c = t & 1; }
    else             { g = 24 + (u - 72),     c = 0; }
    const int qt = 31 - g;
    const int ktlo = c * 8;
    const int kthi = min(ktlo + 7, qt);
    const int nkt = kthi - ktlo + 1;

    const int b = bh / 12, h = bh % 12;
    const int tid = threadIdx.x, w = tid >> 6, l = tid & 63;
    const int l15 = l & 15, lg = l >> 4;
    const size_t headoff = (size_t)b * SEQ * D_MODEL + h * 64;
    const size_t vhead = ((size_t)(b * 12 + h)) << 17;
    const int sc8 = ((l & 7) ^ ((l >> 3) & 7)) * 8;
    const int srow = w * 16 + (l >> 3);

    // Q B-frags, pre-scaled by log2(e)/8 (exp2-domain scores)
    const float QS = 0.125f * 1.44269504088896f;
    bf16x8 qf[2];
    {
        const uint16_t* qp = Q + headoff + (size_t)(qt * 64 + w * 16 + l15) * D_MODEL + lg * 8;
        #pragma unroll
        for (int ds = 0; ds < 2; ++ds) {
            bf16x8 qv = *(const bf16x8*)(qp + ds * 32);
            #pragma unroll
            for (int j = 0; j < 8; ++j)
                qf[ds][j] = (short)f2bf(bf2f((uint16_t)qv[j]) * QS);
        }
    }

    float m_ = -3e38f, l_ = 0.f;
    f32x4 oacc[4];
    #pragma unroll
    for (int ni = 0; ni < 4; ++ni) oacc[ni] = (f32x4){0.f, 0.f, 0.f, 0.f};
    const int qglob = qt * 64 + w * 16 + l15;

    auto stage = [&](int buf, int kt) {
        const uint16_t* ksrc = K + headoff + (size_t)(kt * 64 + srow) * D_MODEL + sc8;
        glds16(ksrc, &ks[buf][w * 1024]);
        glds16(ksrc + 8 * D_MODEL, &ks[buf][w * 1024 + 512]);
        const uint16_t* vsrc = Vt + vhead + (size_t)srow * SEQ + kt * 64 + sc8;
        glds16(vsrc, &vs[buf][w * 1024]);
        glds16(vsrc + 8 * SEQ, &vs[buf][w * 1024 + 512]);
    };

    stage(0, ktlo);
    for (int it = 0; it < nkt; ++it) {
        const int kt = ktlo + it;
        const int cur = it & 1;
        __syncthreads();
        if (it + 1 < nkt) stage(cur ^ 1, kt + 1);

        // S^T[key][q] = K · Qs^T
        f32x4 sacc[4];
        #pragma unroll
        for (int ki = 0; ki < 4; ++ki) sacc[ki] = (f32x4){0.f, 0.f, 0.f, 0.f};
        __builtin_amdgcn_s_setprio(1);
        #pragma unroll
        for (int ds = 0; ds < 2; ++ds)
            #pragma unroll
            for (int ki = 0; ki < 4; ++ki) {
                int byte = (ki * 16 + l15) * 128 + ((((ds << 2) + lg) ^ (l15 & 7)) << 4);
                bf16x8 ak = *(const bf16x8*)((const char*)&ks[cur][0] + byte);
                sacc[ki] = __builtin_amdgcn_mfma_f32_16x16x32_bf16(ak, qf[ds], sacc[ki], 0, 0, 0);
            }
        __builtin_amdgcn_s_setprio(0);

        const bool diag = (kt == qt);
        float sv[16];
        #pragma unroll
        for (int ki = 0; ki < 4; ++ki)
            #pragma unroll
            for (int r = 0; r < 4; ++r) {
                float s = sacc[ki][r];
                if (diag) {
                    int key = kt * 64 + ki * 16 + lg * 4 + r;
                    if (key > qglob) s = -3e38f;
                }
                sv[ki * 4 + r] = s;
            }
        // max tree (max3-fusable)
        float mx = fmaxf(fmaxf(sv[0], sv[1]), sv[2]);
        #pragma unroll
        for (int i = 3; i < 15; i += 2) mx = fmaxf(fmaxf(mx, sv[i]), sv[i + 1]);
        mx = fmaxf(mx, sv[15]);
        mx = fmaxf(mx, __shfl_xor(mx, 16));
        mx = fmaxf(mx, __shfl_xor(mx, 32));
        if (__any(mx > m_ + 11.54f)) {         // defer-max (T13), log2 units
            float mnew = fmaxf(m_, mx);
            float alpha = __builtin_amdgcn_exp2f(m_ - mnew);
            l_ *= alpha;
            float a0 = __shfl(alpha, lg * 4 + 0), a1 = __shfl(alpha, lg * 4 + 1);
            float a2 = __shfl(alpha, lg * 4 + 2), a3 = __shfl(alpha, lg * 4 + 3);
            #pragma unroll
            for (int ni = 0; ni < 4; ++ni) {
                oacc[ni][0] *= a0; oacc[ni][1] *= a1;
                oacc[ni][2] *= a2; oacc[ni][3] *= a3;
            }
            m_ = mnew;
        }
        float sum = 0.f;
        uint32_t pk[8];
        #pragma unroll
        for (int i = 0; i < 16; i += 2) {
            float p0 = __builtin_amdgcn_exp2f(sv[i] - m_);
            float p1 = __builtin_amdgcn_exp2f(sv[i + 1] - m_);
            sum += p0 + p1;
            pk[i >> 1] = cvtpk(p0, p1);
        }
        sum += __shfl_xor(sum, 16);
        sum += __shfl_xor(sum, 32);
        l_ += sum;

        uint16_t* psw = &ps[w][0];
        #pragma unroll
        for (int ki = 0; ki < 4; ++ki) {
            int byte = (l15 * 128 + ki * 32 + lg * 8) ^ ((l15 & 7) << 4);
            *(uint2*)((char*)psw + byte) = make_uint2(pk[ki * 2], pk[ki * 2 + 1]);
        }
        asm volatile("s_waitcnt lgkmcnt(0)" ::: "memory");
        __builtin_amdgcn_sched_barrier(0);

        __builtin_amdgcn_s_setprio(1);
        #pragma unroll
        for (int kss = 0; kss < 2; ++kss) {
            int pbyte = l15 * 128 + ((((kss << 2) + lg) ^ (l15 & 7)) << 4);
            bf16x8 ap = *(const bf16x8*)((const char*)psw + pbyte);
            #pragma unroll
            for (int ni = 0; ni < 4; ++ni) {
                int vbyte = (ni * 16 + l15) * 128 + ((((kss << 2) + lg) ^ (l15 & 7)) << 4);
                bf16x8 bv = *(const bf16x8*)((const char*)&vs[cur][0] + vbyte);
                oacc[ni] = __builtin_amdgcn_mfma_f32_16x16x32_bf16(ap, bv, oacc[ni], 0, 0, 0);
            }
        }
        __builtin_amdgcn_s_setprio(0);
    }

    // Epilogue: normalized partial O (bf16) + combine weight t = m + log2(l)
    float li0 = 1.f / __shfl(l_, lg * 4 + 0), li1 = 1.f / __shfl(l_, lg * 4 + 1);
    float li2 = 1.f / __shfl(l_, lg * 4 + 2), li3 = 1.f / __shfl(l_, lg * 4 + 3);
    uint16_t* op = (bx < 1536) ? (pO1 + (size_t)bx * 4096)
                               : (pO2 + (size_t)(bx - 1536) * 4096);
    #pragma unroll
    for (int ni = 0; ni < 4; ++ni) {
        int col = ni * 16 + l15;
        int rbase = (w * 16 + lg * 4) * 64 + col;
        op[rbase + 0 * 64] = f2bf(oacc[ni][0] * li0);
        op[rbase + 1 * 64] = f2bf(oacc[ni][1] * li1);
        op[rbase + 2 * 64] = f2bf(oacc[ni][2] * li2);
        op[rbase + 3 * 64] = f2bf(oacc[ni][3] * li3);
    }
    if (lg == 0)
        tbuf[(size_t)bx * 64 + w * 16 + l15] = m_ + __log2f(l_);
}

// ---------------------------------------------------------------------------
// Combine partial chunks per (bh, qt): O = sum_c 2^(t_c - tmax) * Ohat_c / denom.
// Grid 768 blocks; thread -> (q = tid/4, d-range = (tid&3)*16 .. +15).
// ---------------------------------------------------------------------------
__global__ __launch_bounds__(256) void attn_combine(const uint16_t* __restrict__ pO1,
                                                    const uint16_t* __restrict__ pO2,
                                                    const float* __restrict__ tbuf,
                                                    uint16_t* __restrict__ Obf) {
    __shared__ float t_lds[4][64];
    const int bx = blockIdx.x;
    const int qt = bx & 31, bh = bx >> 5;
    const int b = bh / 12, h = bh % 12;
    const int g = 31 - qt;
    const int u_base = (g < 8) ? 4 * g : (g < 16) ? 32 + 3 * (g - 8)
                     : (g < 24) ? 56 + 2 * (g - 16) : 72 + (g - 24);
    const int nc = (g < 8) ? 4 : (g < 16) ? 3 : (g < 24) ? 2 : 1;
    const int tid = threadIdx.x;
    if (tid < nc * 64) {
        int c = tid >> 6, q = tid & 63;
        t_lds[c][q] = tbuf[(size_t)((u_base + c) * 24 + bh) * 64 + q];
    }
    __syncthreads();

    const int q = tid >> 2, d0 = (tid & 3) * 16;
    float tmax = t_lds[0][q];
    for (int c = 1; c < nc; ++c) tmax = fmaxf(tmax, t_lds[c][q]);
    float acc[16];
    #pragma unroll
    for (int j = 0; j < 16; ++j) acc[j] = 0.f;
    float denom = 0.f;
    for (int c = 0; c < nc; ++c) {
        float wgt = __builtin_amdgcn_exp2f(t_lds[c][q] - tmax);
        denom += wgt;
        int ug = (u_base + c) * 24 + bh;
        const uint16_t* op = (ug < 1536) ? (pO1 + (size_t)ug * 4096)
                                         : (pO2 + (size_t)(ug - 1536) * 4096);
        bf16x8 v0 = *(const bf16x8*)(op + q * 64 + d0);
        bf16x8 v1 = *(const bf16x8*)(op + q * 64 + d0 + 8);
        #pragma unroll
        for (int j = 0; j < 8; ++j) {
            acc[j]     += bf2f((uint16_t)v0[j]) * wgt;
            acc[8 + j] += bf2f((uint16_t)v1[j]) * wgt;
        }
    }
    float inv = 1.f / denom;
    uint32_t outp[8];
    #pragma unroll
    for (int j = 0; j < 8; ++j)
        outp[j] = cvtpk(acc[2 * j] * inv, acc[2 * j + 1] * inv);
    size_t rb = (size_t)(b * SEQ + qt * 64 + q) * D_MODEL + h * 64 + d0;
    *(uint4*)(Obf + rb)     = make_uint4(outp[0], outp[1], outp[2], outp[3]);
    *(uint4*)(Obf + rb + 8) = make_uint4(outp[4], outp[5], outp[6], outp[7]);
}

// ---------------------------------------------------------------------------
// Workspace (bytes):
//   wsA @ 0 (262144) | wsB @ 262144 (4718592)       [dead after buildC]
//   Wbf @ 4980736 (4718592) bf16 [4][out][in]        [live until o-proj]
//   xbf @ 9699328 (6291456)                          [dead after gemm<1>]
//     -> attn partial units 1536..1919 @ 9699328 (3145728)
//     -> tbuf @ 12845056 (491520)
//   Qbf @ 15990784 | Kbf @ 22282240 | Vtbf @ 28573696 | Obf @ 34865152
//   d_out (12582912 B) = attn partial units 0..1535 (fully overwritten by o-proj)
// ---------------------------------------------------------------------------
extern "C" void kernel_launch(void* const* d_in, const int* in_sizes, int n_in,
                              void* d_out, int out_size, void* d_ws, size_t ws_size,
                              hipStream_t stream) {
    const float* x = (const float*)d_in[0];
    TTPtrs P;
    const float* biases[4];
    const int base[4] = {2, 7, 12, 17};  // q, k, v, o parameter groups
    for (int t = 0; t < 4; t++) {
        P.c0[t] = (const float*)d_in[base[t] + 0];
        P.c1[t] = (const float*)d_in[base[t] + 1];
        P.c2[t] = (const float*)d_in[base[t] + 2];
        P.c3[t] = (const float*)d_in[base[t] + 3];
        biases[t] = (const float*)d_in[base[t] + 4];
    }

    char* ws = (char*)d_ws;
    float* wsA = (float*)(ws + 0);
    float* wsB = (float*)(ws + 262144);
    uint16_t* Wbf = (uint16_t*)(ws + 4980736);
    uint16_t* xbf = (uint16_t*)(ws + 9699328);
    uint16_t* pO2 = (uint16_t*)(ws + 9699328);     // overlaps xbf (dead by attn)
    float* tbuf = (float*)(ws + 12845056);
    uint16_t* Qbf = (uint16_t*)(ws + 15990784);
    uint16_t* Kbf = (uint16_t*)(ws + 22282240);
    uint16_t* Vtbf = (uint16_t*)(ws + 28573696);
    uint16_t* Obf = (uint16_t*)(ws + 34865152);
    uint16_t* pO1 = (uint16_t*)d_out;              // d_out as scratch (rewritten by o-proj)
    (void)Kbf;

    pre_kernel<<<dim3(256 + 3072), 256, 0, stream>>>(P, wsA, x, xbf);
    tt_buildB<<<dim3(1152, 4), 256, 0, stream>>>(P, wsA, wsB);
    tt_buildC<<<dim3(256, 4), 256, 0, stream>>>(P, wsB, Wbf);

    // q, k projections (bf16, row-major); v written transposed to Vtbf
    gemm_mfma<1><<<dim3(32, 6, 3), 256, 0, stream>>>(xbf, Wbf, biases[0], biases[1],
                                                     biases[2], (void*)Qbf, Vtbf);
    // chunked causal attention -> partials, then combine -> Obf
    attn_mfma<<<dim3(1920), 256, 0, stream>>>(Qbf, Kbf, Vtbf, pO1, pO2, tbuf);
    attn_combine<<<dim3(768), 256, 0, stream>>>(pO1, pO2, tbuf, Obf);

    // output projection (fp32 out -> d_out)
    gemm_mfma<0><<<dim3(32, 6, 1), 256, 0, stream>>>(Obf, Wbf + 3 * (size_t)W_ELEMS,
                                                     biases[3], biases[3], biases[3],
                                                     d_out, nullptr);
}